// Round 7
// baseline (243.525 us; speedup 1.0000x reference)
//
#include <hip/hip_runtime.h>
#include <stdint.h>

#define B_TOT 4096

// ---- output offsets (floats) ----
#define OFF_ZL 0
#define OFF_ZH 40960
#define OFF_MU 45056
#define OFF_LV 53248
#define OFF_UO 61440
#define OFF_XL 69632
#define OFF_T1 16846848
#define OFF_T2 16977920

typedef __attribute__((ext_vector_type(8))) short bf16x8;
typedef __attribute__((ext_vector_type(4))) float f32x4;

// bf16 round-to-nearest-even from fp32 (finite values)
__device__ __forceinline__ unsigned short f2b(float f) {
  unsigned int u = __float_as_uint(f);
  return (unsigned short)((u + 0x7FFFu + ((u >> 16) & 1u)) >> 16);
}
__device__ __forceinline__ float b2f(unsigned short b) {
  return __uint_as_float(((unsigned int)b) << 16);
}

// ---------------- threefry2x32 (bit-exact JAX, partitionable path) ----------------
#define TF_ROUND(r) do { x0 += x1; x1 = (x1 << (r)) | (x1 >> (32-(r))); x1 ^= x0; } while(0)

__device__ __forceinline__ void threefry(uint32_t k0, uint32_t k1,
                                         uint32_t c0, uint32_t c1,
                                         uint32_t& o0, uint32_t& o1) {
  uint32_t ks2 = k0 ^ k1 ^ 0x1BD11BDAu;
  uint32_t x0 = c0 + k0, x1 = c1 + k1;
  TF_ROUND(13); TF_ROUND(15); TF_ROUND(26); TF_ROUND(6);
  x0 += k1;  x1 += ks2 + 1u;
  TF_ROUND(17); TF_ROUND(29); TF_ROUND(16); TF_ROUND(24);
  x0 += ks2; x1 += k0 + 2u;
  TF_ROUND(13); TF_ROUND(15); TF_ROUND(26); TF_ROUND(6);
  x0 += k0;  x1 += k1 + 3u;
  TF_ROUND(17); TF_ROUND(29); TF_ROUND(16); TF_ROUND(24);
  x0 += k1;  x1 += ks2 + 4u;
  TF_ROUND(13); TF_ROUND(15); TF_ROUND(26); TF_ROUND(6);
  x0 += ks2; x1 += k0 + 5u;
  o0 = x0; o1 = x1;
}

__device__ __forceinline__ uint32_t tf_bits32(uint32_t k0, uint32_t k1, uint32_t j) {
  uint32_t r0, r1;
  threefry(k0, k1, 0u, j, r0, r1);
  return r0 ^ r1;
}

// XLA ErfInv f32 (Giles polynomial)
__device__ __forceinline__ float erfinv_xla(float x) {
  float w = -log1pf(-x * x);
  float p;
  if (w < 5.0f) {
    w -= 2.5f;
    p = 2.81022636e-08f;
    p = fmaf(p, w, 3.43273939e-07f);
    p = fmaf(p, w, -3.5233877e-06f);
    p = fmaf(p, w, -4.39150654e-06f);
    p = fmaf(p, w, 0.00021858087f);
    p = fmaf(p, w, -0.00125372503f);
    p = fmaf(p, w, -0.00417768164f);
    p = fmaf(p, w, 0.246640727f);
    p = fmaf(p, w, 1.50140941f);
  } else {
    w = sqrtf(w) - 3.0f;
    p = -0.000200214257f;
    p = fmaf(p, w, 0.000100950558f);
    p = fmaf(p, w, 0.00134934322f);
    p = fmaf(p, w, -0.00367342844f);
    p = fmaf(p, w, 0.00573950773f);
    p = fmaf(p, w, -0.0076224613f);
    p = fmaf(p, w, 0.00943887047f);
    p = fmaf(p, w, 1.00167406f);
    p = fmaf(p, w, 2.83297682f);
  }
  return p * x;
}

// ---------------- prep: bf16-transpose decoder weights ----------------
__global__ __launch_bounds__(256) void k_prep(const float* __restrict__ w3,
    const float* __restrict__ w2, unsigned short* __restrict__ w3t,
    unsigned short* __restrict__ w2t) {
  int idx = blockIdx.x * 256 + threadIdx.x;
  unsigned short tmp[8];
  if (idx < 32768) {
    int np = idx >> 5, k0 = (idx & 31) * 8;
    int ic = np & 63, pos = np >> 6;
#pragma unroll
    for (int i = 0; i < 8; ++i)
      tmp[i] = f2b(w3[(size_t)(k0 + i) * 1024 + ic * 16 + pos]);
    *(bf16x8*)(w3t + (size_t)np * 256 + k0) = *(bf16x8*)tmp;
  } else if (idx < 32768 + 2048) {
    int j = idx - 32768;
    int n = j >> 3, k0 = (j & 7) * 8;
#pragma unroll
    for (int i = 0; i < 8; ++i)
      tmp[i] = f2b(w2[(size_t)(k0 + i) * 256 + n]);
    *(bf16x8*)(w2t + (size_t)n * 64 + k0) = *(bf16x8*)tmp;
  }
}

// ---------------- fused conv1+conv2: x (B,1,64,64) -> h2 (b, oc*16+pos), relu ------
// Per block: 4 batches (64 GEMM rows). conv1 computed into LDS im2col As[k][row]
// in two oc-halves (As[128][68] = 35 KB), then conv2g's proven 4x4 micro-kernel.
// k-order bit-identical to the previous conv1 + conv2g pipeline.
__global__ __launch_bounds__(256) void k_conv12(const float* __restrict__ x,
    const float* __restrict__ w1c, const float* __restrict__ b1c,
    const float* __restrict__ w2, const float* __restrict__ b2c,
    float* __restrict__ h2) {
  __shared__ __align__(16) float As[128][68];
  __shared__ __align__(16) float Bs[16][68];
  __shared__ __align__(16) float w1s[256];
  __shared__ float b1v[16];
  int t = threadIdx.x;
  int blk = blockIdx.x;                 // 1024 blocks
  w1s[t] = w1c[t];
  if (t < 16) b1v[t] = b1c[t];
  __syncthreads();
  int i = t >> 4, j = t & 15;           // conv1 pixel (i,j) in 16x16
  int pos = (i >> 2) * 4 + (j >> 2);
  int pq  = (i & 3) * 4 + (j & 3);
  int tx = t & 15, ty = t >> 4;
  int lrB = t >> 2, lkB = (t & 3) * 4;
  float acc[4][4] = {};
  const float* xbase = x + (size_t)blk * 4 * 4096;

  for (int half = 0; half < 2; ++half) {
    // conv1 for oc in [half*8, half*8+8) across 4 batches -> As[(oc&7)*16+pq][row]
    for (int bb = 0; bb < 4; ++bb) {
      const float* xb = xbase + bb * 4096;
      float4 xv[4];
#pragma unroll
      for (int p = 0; p < 4; ++p)
        xv[p] = *(const float4*)(xb + (4 * i + p) * 64 + 4 * j);
      float a1[8];
#pragma unroll
      for (int o = 0; o < 8; ++o) a1[o] = b1v[half * 8 + o];
#pragma unroll
      for (int p = 0; p < 4; ++p) {
        float4 xp = xv[p];
#pragma unroll
        for (int o = 0; o < 8; ++o) {
          float4 wv = *(const float4*)(w1s + (half * 8 + o) * 16 + p * 4);
          a1[o] = fmaf(xp.x, wv.x, a1[o]);
          a1[o] = fmaf(xp.y, wv.y, a1[o]);
          a1[o] = fmaf(xp.z, wv.z, a1[o]);
          a1[o] = fmaf(xp.w, wv.w, a1[o]);
        }
      }
      int row = bb * 16 + pos;
#pragma unroll
      for (int o = 0; o < 8; ++o)
        As[o * 16 + pq][row] = fmaxf(a1[o], 0.f);
    }
    // GEMM over this k-half (k order 0..255 sequential across halves)
    for (int k0 = 0; k0 < 128; k0 += 16) {
      float4 bv = *(const float4*)(w2 + (size_t)lrB * 256 + half * 128 + k0 + lkB);
      Bs[lkB + 0][lrB] = bv.x; Bs[lkB + 1][lrB] = bv.y;
      Bs[lkB + 2][lrB] = bv.z; Bs[lkB + 3][lrB] = bv.w;
      __syncthreads();
#pragma unroll
      for (int kk = 0; kk < 16; ++kk) {
        float4 af = *(const float4*)(&As[k0 + kk][ty * 4]);
        float4 bf = *(const float4*)(&Bs[kk][tx * 4]);
        float av[4] = {af.x, af.y, af.z, af.w};
        float bw[4] = {bf.x, bf.y, bf.z, bf.w};
#pragma unroll
        for (int ii = 0; ii < 4; ++ii)
#pragma unroll
          for (int jj = 0; jj < 4; ++jj)
            acc[ii][jj] = fmaf(av[ii], bw[jj], acc[ii][jj]);
      }
      __syncthreads();
    }
  }
  float4 bb4 = *(const float4*)(b2c + tx * 4);
  float bb[4] = {bb4.x, bb4.y, bb4.z, bb4.w};
#pragma unroll
  for (int ii = 0; ii < 4; ++ii) {
    int row = blk * 64 + ty * 4 + ii;
    int b = row >> 4, pos2 = row & 15;
    float* hp = h2 + (size_t)b * 1024 + pos2;
#pragma unroll
    for (int jj = 0; jj < 4; ++jj)
      hp[(tx * 4 + jj) * 16] = fmaxf(acc[ii][jj] + bb[jj], 0.f);
  }
}

// ---------------- conv3 K-split partial (fp32, encoder precision) ----------
__global__ __launch_bounds__(256) void k_conv3p(const float* __restrict__ A,
    const float* __restrict__ w3, float* __restrict__ part) {
  __shared__ __align__(16) float As[16][68];
  __shared__ __align__(16) float Bs[16][68];
  int t = threadIdx.x;
  int m0 = blockIdx.x * 64, n0 = blockIdx.y * 64;
  int kb = blockIdx.z * 256;
  int tx = t & 15, ty = t >> 4;
  float acc[4][4] = {};
  int lr = t >> 2, lk = (t & 3) * 4;
  for (int k0 = kb; k0 < kb + 256; k0 += 16) {
    float4 a  = *(const float4*)(A  + (size_t)(m0 + lr) * 1024 + k0 + lk);
    float4 bv = *(const float4*)(w3 + (size_t)(n0 + lr) * 1024 + k0 + lk);
    As[lk + 0][lr] = a.x; As[lk + 1][lr] = a.y; As[lk + 2][lr] = a.z; As[lk + 3][lr] = a.w;
    Bs[lk + 0][lr] = bv.x; Bs[lk + 1][lr] = bv.y; Bs[lk + 2][lr] = bv.z; Bs[lk + 3][lr] = bv.w;
    __syncthreads();
#pragma unroll
    for (int kk = 0; kk < 16; ++kk) {
      float4 af = *(const float4*)(&As[kk][ty * 4]);
      float4 bf = *(const float4*)(&Bs[kk][tx * 4]);
      float av[4] = {af.x, af.y, af.z, af.w};
      float bb[4] = {bf.x, bf.y, bf.z, bf.w};
#pragma unroll
      for (int ii = 0; ii < 4; ++ii)
#pragma unroll
        for (int jj = 0; jj < 4; ++jj)
          acc[ii][jj] = fmaf(av[ii], bb[jj], acc[ii][jj]);
    }
    __syncthreads();
  }
  float* pc = part + (size_t)blockIdx.z * 1048576;
#pragma unroll
  for (int ii = 0; ii < 4; ++ii) {
    int row = m0 + ty * 4 + ii;
    *(float4*)(pc + (size_t)row * 256 + n0 + tx * 4) =
        make_float4(acc[ii][0], acc[ii][1], acc[ii][2], acc[ii][3]);
  }
}

__global__ __launch_bounds__(256) void k_c3red(const float* __restrict__ part,
    const float* __restrict__ b3, float* __restrict__ h) {
  int idx = blockIdx.x * 256 + threadIdx.x;
  int row = idx >> 6, c4 = (idx & 63) * 4;
  const float* p0 = part + (size_t)row * 256 + c4;
  float4 s  = *(const float4*)(p0);
  float4 s1 = *(const float4*)(p0 + 1048576);
  float4 s2 = *(const float4*)(p0 + 2097152);
  float4 s3 = *(const float4*)(p0 + 3145728);
  float4 bb = *(const float4*)(b3 + c4);
  float4 o;
  o.x = fmaxf(((s.x + s1.x) + s2.x) + s3.x + bb.x, 0.f);
  o.y = fmaxf(((s.y + s1.y) + s2.y) + s3.y + bb.y, 0.f);
  o.z = fmaxf(((s.z + s1.z) + s2.z) + s3.z + bb.z, 0.f);
  o.w = fmaxf(((s.w + s1.w) + s2.w) + s3.w + bb.w, 0.f);
  *(float4*)(h + (size_t)row * 256 + c4) = o;
}

// ---------------- headA: xzxu = relu(h (4096x256) @ [w_xz;w_xu]^T) (4096x64) fp32 ----
__global__ __launch_bounds__(256) void k_headA(const float* __restrict__ A,
    const float* __restrict__ w_xz, const float* __restrict__ w_xu,
    float* __restrict__ xzxu) {
  __shared__ __align__(16) float As[16][68];
  __shared__ __align__(16) float Bs[16][68];
  int t = threadIdx.x;
  int m0 = blockIdx.x * 64;
  int tx = t & 15, ty = t >> 4;
  float acc[4][4] = {};
  int lr = t >> 2, lk = (t & 3) * 4;
  const float* wr = (lr < 32) ? (w_xz + lr * 256) : (w_xu + (lr - 32) * 256);
  for (int k0 = 0; k0 < 256; k0 += 16) {
    float4 a  = *(const float4*)(A + (size_t)(m0 + lr) * 256 + k0 + lk);
    float4 bv = *(const float4*)(wr + k0 + lk);
    As[lk + 0][lr] = a.x; As[lk + 1][lr] = a.y; As[lk + 2][lr] = a.z; As[lk + 3][lr] = a.w;
    Bs[lk + 0][lr] = bv.x; Bs[lk + 1][lr] = bv.y; Bs[lk + 2][lr] = bv.z; Bs[lk + 3][lr] = bv.w;
    __syncthreads();
#pragma unroll
    for (int kk = 0; kk < 16; ++kk) {
      float4 af = *(const float4*)(&As[kk][ty * 4]);
      float4 bf = *(const float4*)(&Bs[kk][tx * 4]);
      float av[4] = {af.x, af.y, af.z, af.w};
      float bb[4] = {bf.x, bf.y, bf.z, bf.w};
#pragma unroll
      for (int ii = 0; ii < 4; ++ii)
#pragma unroll
        for (int jj = 0; jj < 4; ++jj)
          acc[ii][jj] = fmaf(av[ii], bb[jj], acc[ii][jj]);
    }
    __syncthreads();
  }
#pragma unroll
  for (int ii = 0; ii < 4; ++ii) {
    int row = m0 + ty * 4 + ii;
    float4 o;
    o.x = fmaxf(acc[ii][0], 0.f);
    o.y = fmaxf(acc[ii][1], 0.f);
    o.z = fmaxf(acc[ii][2], 0.f);
    o.w = fmaxf(acc[ii][3], 0.f);
    *(float4*)(xzxu + (size_t)row * 64 + tx * 4) = o;
  }
}

// ---------------- headB: small FCs + sampling + transform + x_hat (LDS bf16 tc) -----
// grid 256, 16 batches per block (staging amortized 4x)
__global__ __launch_bounds__(256) void k_headB(
    const float* __restrict__ xzxu,
    const float* __restrict__ w_label,
    const float* __restrict__ w_zd1, const float* __restrict__ w_zd2,
    const float* __restrict__ w_mu, const float* __restrict__ w_logvar,
    const float* __restrict__ tc_w, const float* __restrict__ tc_b,
    float* __restrict__ outp, unsigned short* __restrict__ xhb) {
  __shared__ __align__(16) unsigned short twL[16384];  // 32KB: tc_w bf16 [i][o][c]
  __shared__ __align__(16) unsigned short tbL[8192];   // 16KB: tc_b bf16 [i][o]
  __shared__ float xzs[4][32], xus[4][32];
  __shared__ float zls[4][10], gbs[4][10];
  __shared__ float mus[4][2], lvs[4][2], epss[4][2], uos[4][2];
  __shared__ float t1s[4][32], t2s[4][32];
  __shared__ int zhs[4];
  int t = threadIdx.x;
  int wv = t >> 6, l = t & 63;

  // stage tc_w (16384 f) + tc_b (8192 f) as bf16 -- once per block
  for (int v = t; v < 4096; v += 256) {
    float4 w4 = *(const float4*)(tc_w + (size_t)v * 4);
    unsigned short pk[4] = {f2b(w4.x), f2b(w4.y), f2b(w4.z), f2b(w4.w)};
    *(ushort4*)(twL + v * 4) = *(ushort4*)pk;
  }
  for (int v = t; v < 2048; v += 256) {
    float4 b4 = *(const float4*)(tc_b + (size_t)v * 4);
    unsigned short pk[4] = {f2b(b4.x), f2b(b4.y), f2b(b4.z), f2b(b4.w)};
    *(ushort4*)(tbL + v * 4) = *(ushort4*)pk;
  }

  for (int bi = 0; bi < 4; ++bi) {
    int b = blockIdx.x * 16 + bi * 4 + wv;
    {
      float v = xzxu[(size_t)b * 64 + l];
      if (l < 32) xzs[wv][l] = v; else xus[wv][l - 32] = v;
    }
    __syncthreads();

    if (l < 10) {                       // z_logit
      float acc = 0.f;
#pragma unroll
      for (int k = 0; k < 32; ++k) acc = fmaf(xzs[wv][k], w_label[l * 32 + k], acc);
      zls[wv][l] = acc;
      outp[OFF_ZL + (size_t)b * 10 + l] = acc;
    } else if (l < 12) {                // mu
      int d = l - 10;
      float acc = 0.f;
#pragma unroll
      for (int k = 0; k < 32; ++k) acc = fmaf(xus[wv][k], w_mu[d * 32 + k], acc);
      mus[wv][d] = acc;
      outp[OFF_MU + (size_t)b * 2 + d] = acc;
    } else if (l < 14) {                // logvar
      int d = l - 12;
      float acc = 0.f;
#pragma unroll
      for (int k = 0; k < 32; ++k) acc = fmaf(xus[wv][k], w_logvar[d * 32 + k], acc);
      lvs[wv][d] = acc;
      outp[OFF_LV + (size_t)b * 2 + d] = acc;
    }
    __syncthreads();

    if (l < 10) {                       // gumbel
      uint32_t kc0, kc1;
      threefry(0u, 42u, 0u, 0u, kc0, kc1);
      uint32_t bits = tf_bits32(kc0, kc1, (uint32_t)(b * 10 + l));
      float f = __uint_as_float((bits >> 9) | 0x3F800000u) - 1.0f;
      float u = fmaxf(f, 1.17549435e-38f);
      float g = -logf(-logf(u));
      gbs[wv][l] = zls[wv][l] + g;
    } else if (l < 12) {                // eps (normal)
      int d = l - 10;
      uint32_t ke0, ke1;
      threefry(0u, 42u, 0u, 1u, ke0, ke1);
      uint32_t bits = tf_bits32(ke0, ke1, (uint32_t)(b * 2 + d));
      float f = __uint_as_float((bits >> 9) | 0x3F800000u) - 1.0f;
      float u = fmaxf(f * 2.0f - 0.99999994f, -0.99999994f);
      epss[wv][d] = 1.41421356f * erfinv_xla(u);
    }
    __syncthreads();

    if (l == 0) {                       // argmax
      float best = gbs[wv][0];
      int bi2 = 0;
#pragma unroll
      for (int c = 1; c < 10; ++c) {
        float v = gbs[wv][c];
        if (v > best) { best = v; bi2 = c; }
      }
      zhs[wv] = bi2;
      outp[OFF_ZH + b] = (float)bi2;
    } else if (l < 3) {
      int d = l - 1;
      float sd = expf(0.5f * lvs[wv][d]);
      float uo = fmaf(epss[wv][d], sd, mus[wv][d]);
      uos[wv][d] = uo;
      outp[OFF_UO + (size_t)b * 2 + d] = uo;
    }
    __syncthreads();

    if (l < 32) {
      int zh = zhs[wv];
      float t1 = uos[wv][0] + w_zd1[l * 10 + zh];
      float t2 = uos[wv][1] + w_zd2[l * 10 + zh];
      t1s[wv][l] = t1; t2s[wv][l] = t2;
      outp[OFF_T1 + (size_t)b * 32 + l] = t1;
      outp[OFF_T2 + (size_t)b * 32 + l] = t2;
    }
    __syncthreads();

    {                                   // x_hat from LDS bf16 tc_w/tc_b
      float ax = 0.f, ay = 0.f, az = 0.f, aw = 0.f;
#pragma unroll 4
      for (int i = 0; i < 32; ++i) {
        float t1 = t1s[wv][i], t2 = t2s[wv][i];
        ushort4 wa = *(const ushort4*)(twL + i * 512 + l * 8);
        ushort4 wb = *(const ushort4*)(twL + i * 512 + l * 8 + 4);
        ushort4 tb = *(const ushort4*)(tbL + i * 256 + l * 4);
        float s;
        s = fmaf(t1, b2f(wa.x), fmaf(t2, b2f(wa.y), b2f(tb.x))); ax += fmaxf(s, 0.f);
        s = fmaf(t1, b2f(wa.z), fmaf(t2, b2f(wa.w), b2f(tb.y))); ay += fmaxf(s, 0.f);
        s = fmaf(t1, b2f(wb.x), fmaf(t2, b2f(wb.y), b2f(tb.z))); az += fmaxf(s, 0.f);
        s = fmaf(t1, b2f(wb.z), fmaf(t2, b2f(wb.w), b2f(tb.w))); aw += fmaxf(s, 0.f);
      }
      unsigned short pk[4] = {f2b(ax), f2b(ay), f2b(az), f2b(aw)};
      *(ushort4*)(xhb + (size_t)b * 256 + l * 4) = *(ushort4*)pk;
    }
    __syncthreads();
  }
}

// ---------------- dec3 MFMA: xh_bf16 (4096x256) @ W3t^T -> d3t bf16 (65536x64), relu
__global__ __launch_bounds__(256) void k_dec3m(const unsigned short* __restrict__ xhb,
    const unsigned short* __restrict__ w3t, const float* __restrict__ bias,
    unsigned short* __restrict__ d3t) {
  int t = threadIdx.x;
  int lane = t & 63, wv = t >> 6;
  int m0 = blockIdx.x * 64, n0 = blockIdx.y * 64;
  int l15 = lane & 15, g8 = (lane >> 4) * 8;
  const unsigned short* arow = xhb + (size_t)(m0 + wv * 16 + l15) * 256 + g8;
  const unsigned short* brow = w3t + (size_t)(n0 + l15) * 256 + g8;
  f32x4 acc[4] = {};
  for (int kb = 0; kb < 256; kb += 32) {
    bf16x8 af = *(const bf16x8*)(arow + kb);
#pragma unroll
    for (int ns = 0; ns < 4; ++ns) {
      bf16x8 bf = *(const bf16x8*)(brow + (size_t)ns * 4096 + kb);
      acc[ns] = __builtin_amdgcn_mfma_f32_16x16x32_bf16(af, bf, acc[ns], 0, 0, 0);
    }
  }
  int rbase = (lane >> 4) * 4;
#pragma unroll
  for (int ns = 0; ns < 4; ++ns) {
    int ncol = n0 + ns * 16 + l15;
    float bb = bias[ncol & 63];
#pragma unroll
    for (int r = 0; r < 4; ++r) {
      float v = fmaxf(acc[ns][r] + bb, 0.f);
      d3t[(size_t)(m0 + wv * 16 + rbase + r) * 1024 + ncol] = f2b(v);
    }
  }
}

// ---------------- dec2 MFMA + fused dec1 ----------------
__global__ __launch_bounds__(256) void k_dec2m(const unsigned short* __restrict__ d3t,
    const unsigned short* __restrict__ w2t, const float* __restrict__ b2,
    const float* __restrict__ w1, const float* __restrict__ b1,
    float* __restrict__ outp) {
  __shared__ unsigned short d2L[4][4096];
  __shared__ __align__(16) float w1s[256];
  __shared__ float b1s;
  int t = threadIdx.x;
  int lane = t & 63, wv = t >> 6;
  int m0 = blockIdx.x * 64;
  w1s[t] = w1[t];
  if (t == 0) b1s = b1[0];
  int l15 = lane & 15, g8 = (lane >> 4) * 8;
  const unsigned short* arow = d3t + (size_t)(m0 + wv * 16 + l15) * 64 + g8;
  bf16x8 af0 = *(const bf16x8*)(arow);
  bf16x8 af1 = *(const bf16x8*)(arow + 32);
  const unsigned short* brow = w2t + (size_t)l15 * 64 + g8;
  f32x4 acc[16] = {};
#pragma unroll
  for (int ns = 0; ns < 16; ++ns) {
    bf16x8 bf0 = *(const bf16x8*)(brow + (size_t)ns * 1024);
    bf16x8 bf1 = *(const bf16x8*)(brow + (size_t)ns * 1024 + 32);
    acc[ns] = __builtin_amdgcn_mfma_f32_16x16x32_bf16(af0, bf0, acc[ns], 0, 0, 0);
    acc[ns] = __builtin_amdgcn_mfma_f32_16x16x32_bf16(af1, bf1, acc[ns], 0, 0, 0);
  }
  int rbase = (lane >> 4) * 4;
  int pq_p = l15 >> 2, pq_q = l15 & 3;
#pragma unroll
  for (int ns = 0; ns < 16; ++ns) {
    float bb = b2[ns];
#pragma unroll
    for (int r = 0; r < 4; ++r) {
      int pos = rbase + r;
      float v = fmaxf(acc[ns][r] + bb, 0.f);
      d2L[wv][ns * 256 + ((pos >> 2) * 4 + pq_p) * 16 + (pos & 3) * 4 + pq_q] = f2b(v);
    }
  }
  __syncthreads();
  int bg0 = m0 >> 4;
  for (int c4 = 0; c4 < 16; ++c4) {
    int v = t + 256 * c4;
    int bp = v >> 10;
    int I = (v & 1023) >> 4;
    int jpix = v & 15;
    int ipix = I >> 2, pp = I & 3;
    const unsigned short* dl = &d2L[bp][ipix * 16 + jpix];
    float4 o = make_float4(b1s, b1s, b1s, b1s);
#pragma unroll
    for (int c = 0; c < 16; ++c) {
      float dv = b2f(dl[c * 256]);
      float4 wv4 = *(const float4*)(w1s + c * 16 + pp * 4);
      o.x = fmaf(dv, wv4.x, o.x);
      o.y = fmaf(dv, wv4.y, o.y);
      o.z = fmaf(dv, wv4.z, o.z);
      o.w = fmaf(dv, wv4.w, o.w);
    }
    *(float4*)(outp + (size_t)(bg0 + bp) * 4096 + I * 64 + jpix * 4) = o;
  }
}

extern "C" void kernel_launch(void* const* d_in, const int* in_sizes, int n_in,
                              void* d_out, int out_size, void* d_ws, size_t ws_size,
                              hipStream_t stream) {
  const float* x       = (const float*)d_in[0];
  const float* conv1_w = (const float*)d_in[3];
  const float* conv1_b = (const float*)d_in[4];
  const float* conv2_w = (const float*)d_in[5];
  const float* conv2_b = (const float*)d_in[6];
  const float* conv3_w = (const float*)d_in[7];
  const float* conv3_b = (const float*)d_in[8];
  const float* w_xz    = (const float*)d_in[9];
  const float* w_label = (const float*)d_in[10];
  const float* w_zd1   = (const float*)d_in[11];
  const float* w_zd2   = (const float*)d_in[12];
  const float* w_xu    = (const float*)d_in[13];
  const float* w_mu    = (const float*)d_in[14];
  const float* w_logvar= (const float*)d_in[15];
  const float* tc_w    = (const float*)d_in[16];
  const float* tc_b    = (const float*)d_in[17];
  const float* dec3_w  = (const float*)d_in[18];
  const float* dec3_b  = (const float*)d_in[19];
  const float* dec2_w  = (const float*)d_in[20];
  const float* dec2_b  = (const float*)d_in[21];
  const float* dec1_w  = (const float*)d_in[22];
  const float* dec1_b  = (const float*)d_in[23];

  float* out = (float*)d_out;
  float* ws  = (float*)d_ws;

  float* big = out + OFF_XL;                         // conv3 partials -> final out
  float* h2  = ws;                                   // fp32 h2 [0 .. 4M)
  float* h   = ws + 4194304;                         // fp32 h  [4M .. 5.24M)
  unsigned short* d3t = (unsigned short*)ws;         // bf16 d3t reuses [0 .. 2M floats)
  unsigned short* xhb = (unsigned short*)(ws + 5242880);   // bf16 xh (0.5M float-slots)
  unsigned short* w3t = (unsigned short*)(ws + 5767168);   // bf16 W3t (128K float-slots)
  unsigned short* w2t = (unsigned short*)(ws + 5898240);   // bf16 W2t (8K float-slots)
  float* xzxu = ws + 5906432;                        // fp32 xzxu (256K floats)

  k_prep<<<136, 256, 0, stream>>>(dec3_w, dec2_w, w3t, w2t);
  k_conv12<<<1024, 256, 0, stream>>>(x, conv1_w, conv1_b, conv2_w, conv2_b, h2);
  k_conv3p<<<dim3(64, 4, 4), 256, 0, stream>>>(h2, conv3_w, big);
  k_c3red<<<1024, 256, 0, stream>>>(big, conv3_b, h);
  k_headA<<<64, 256, 0, stream>>>(h, w_xz, w_xu, xzxu);
  k_headB<<<256, 256, 0, stream>>>(xzxu, w_label, w_zd1, w_zd2, w_mu,
                                   w_logvar, tc_w, tc_b, out, xhb);
  k_dec3m<<<dim3(64, 16), 256, 0, stream>>>(xhb, w3t, dec3_b, d3t);
  k_dec2m<<<1024, 256, 0, stream>>>(d3t, w2t, dec2_b, dec1_w, dec1_b, big);
}

// Round 8
// 199.379 us; speedup vs baseline: 1.2214x; 1.2214x over previous
//
#include <hip/hip_runtime.h>
#include <stdint.h>

#define B_TOT 4096

// ---- output offsets (floats) ----
#define OFF_ZL 0
#define OFF_ZH 40960
#define OFF_MU 45056
#define OFF_LV 53248
#define OFF_UO 61440
#define OFF_XL 69632
#define OFF_T1 16846848
#define OFF_T2 16977920

typedef __attribute__((ext_vector_type(8))) short bf16x8;
typedef __attribute__((ext_vector_type(4))) float f32x4;

// bf16 round-to-nearest-even from fp32 (finite values)
__device__ __forceinline__ unsigned short f2b(float f) {
  unsigned int u = __float_as_uint(f);
  return (unsigned short)((u + 0x7FFFu + ((u >> 16) & 1u)) >> 16);
}
__device__ __forceinline__ float b2f(unsigned short b) {
  return __uint_as_float(((unsigned int)b) << 16);
}

// ---------------- threefry2x32 (bit-exact JAX, partitionable path) ----------------
#define TF_ROUND(r) do { x0 += x1; x1 = (x1 << (r)) | (x1 >> (32-(r))); x1 ^= x0; } while(0)

__device__ __forceinline__ void threefry(uint32_t k0, uint32_t k1,
                                         uint32_t c0, uint32_t c1,
                                         uint32_t& o0, uint32_t& o1) {
  uint32_t ks2 = k0 ^ k1 ^ 0x1BD11BDAu;
  uint32_t x0 = c0 + k0, x1 = c1 + k1;
  TF_ROUND(13); TF_ROUND(15); TF_ROUND(26); TF_ROUND(6);
  x0 += k1;  x1 += ks2 + 1u;
  TF_ROUND(17); TF_ROUND(29); TF_ROUND(16); TF_ROUND(24);
  x0 += ks2; x1 += k0 + 2u;
  TF_ROUND(13); TF_ROUND(15); TF_ROUND(26); TF_ROUND(6);
  x0 += k0;  x1 += k1 + 3u;
  TF_ROUND(17); TF_ROUND(29); TF_ROUND(16); TF_ROUND(24);
  x0 += k1;  x1 += ks2 + 4u;
  TF_ROUND(13); TF_ROUND(15); TF_ROUND(26); TF_ROUND(6);
  x0 += ks2; x1 += k0 + 5u;
  o0 = x0; o1 = x1;
}

__device__ __forceinline__ uint32_t tf_bits32(uint32_t k0, uint32_t k1, uint32_t j) {
  uint32_t r0, r1;
  threefry(k0, k1, 0u, j, r0, r1);
  return r0 ^ r1;
}

// XLA ErfInv f32 (Giles polynomial)
__device__ __forceinline__ float erfinv_xla(float x) {
  float w = -log1pf(-x * x);
  float p;
  if (w < 5.0f) {
    w -= 2.5f;
    p = 2.81022636e-08f;
    p = fmaf(p, w, 3.43273939e-07f);
    p = fmaf(p, w, -3.5233877e-06f);
    p = fmaf(p, w, -4.39150654e-06f);
    p = fmaf(p, w, 0.00021858087f);
    p = fmaf(p, w, -0.00125372503f);
    p = fmaf(p, w, -0.00417768164f);
    p = fmaf(p, w, 0.246640727f);
    p = fmaf(p, w, 1.50140941f);
  } else {
    w = sqrtf(w) - 3.0f;
    p = -0.000200214257f;
    p = fmaf(p, w, 0.000100950558f);
    p = fmaf(p, w, 0.00134934322f);
    p = fmaf(p, w, -0.00367342844f);
    p = fmaf(p, w, 0.00573950773f);
    p = fmaf(p, w, -0.0076224613f);
    p = fmaf(p, w, 0.00943887047f);
    p = fmaf(p, w, 1.00167406f);
    p = fmaf(p, w, 2.83297682f);
  }
  return p * x;
}

// ---------------- prep: bf16-transpose decoder weights ----------------
__global__ __launch_bounds__(256) void k_prep(const float* __restrict__ w3,
    const float* __restrict__ w2, unsigned short* __restrict__ w3t,
    unsigned short* __restrict__ w2t) {
  int idx = blockIdx.x * 256 + threadIdx.x;
  unsigned short tmp[8];
  if (idx < 32768) {
    int np = idx >> 5, k0 = (idx & 31) * 8;
    int ic = np & 63, pos = np >> 6;
#pragma unroll
    for (int i = 0; i < 8; ++i)
      tmp[i] = f2b(w3[(size_t)(k0 + i) * 1024 + ic * 16 + pos]);
    *(bf16x8*)(w3t + (size_t)np * 256 + k0) = *(bf16x8*)tmp;
  } else if (idx < 32768 + 2048) {
    int j = idx - 32768;
    int n = j >> 3, k0 = (j & 7) * 8;
#pragma unroll
    for (int i = 0; i < 8; ++i)
      tmp[i] = f2b(w2[(size_t)(k0 + i) * 256 + n]);
    *(bf16x8*)(w2t + (size_t)n * 64 + k0) = *(bf16x8*)tmp;
  }
}

// ---------------- conv1: x (B,1,64,64) -> h1t (B, pos(16), ic*16+pq) im2col, relu ----
__global__ __launch_bounds__(256) void k_conv1(const float* __restrict__ x,
    const float* __restrict__ w, const float* __restrict__ bias,
    float* __restrict__ h1t) {
  __shared__ __align__(16) float ws[256];
  __shared__ float bs[16];
  int b = blockIdx.x, t = threadIdx.x;
  ws[t] = w[t];
  if (t < 16) bs[t] = bias[t];
  __syncthreads();
  int i = t >> 4, j = t & 15;
  const float* xb = x + (size_t)b * 4096;
  float4 xv[4];
#pragma unroll
  for (int p = 0; p < 4; ++p)
    xv[p] = *(const float4*)(xb + (4 * i + p) * 64 + 4 * j);
  float acc[16];
#pragma unroll
  for (int oc = 0; oc < 16; ++oc) acc[oc] = bs[oc];
#pragma unroll
  for (int p = 0; p < 4; ++p) {
    float4 xp = xv[p];
#pragma unroll
    for (int oc = 0; oc < 16; ++oc) {
      float4 wv = *(const float4*)(ws + oc * 16 + p * 4);
      acc[oc] = fmaf(xp.x, wv.x, acc[oc]);
      acc[oc] = fmaf(xp.y, wv.y, acc[oc]);
      acc[oc] = fmaf(xp.z, wv.z, acc[oc]);
      acc[oc] = fmaf(xp.w, wv.w, acc[oc]);
    }
  }
  float* hb = h1t + (size_t)b * 4096 + ((i >> 2) * 4 + (j >> 2)) * 256
            + (i & 3) * 4 + (j & 3);
#pragma unroll
  for (int oc = 0; oc < 16; ++oc)
    hb[oc * 16] = fmaxf(acc[oc], 0.0f);
}

// ---------------- conv2 as GEMM: h1t (65536x256) @ w2(64x256)^T -> h2 (b, oc*16+pos), relu
__global__ __launch_bounds__(256) void k_conv2g(const float* __restrict__ A,
    const float* __restrict__ Bw, const float* __restrict__ bias,
    float* __restrict__ h2) {
  __shared__ __align__(16) float As[16][68];
  __shared__ __align__(16) float Bs[16][68];
  int t = threadIdx.x;
  int m0 = blockIdx.x * 64;
  int tx = t & 15, ty = t >> 4;
  float acc[4][4] = {};
  int lr = t >> 2, lk = (t & 3) * 4;
  for (int k0 = 0; k0 < 256; k0 += 16) {
    float4 a  = *(const float4*)(A  + (size_t)(m0 + lr) * 256 + k0 + lk);
    float4 bv = *(const float4*)(Bw + (size_t)lr * 256 + k0 + lk);
    As[lk + 0][lr] = a.x; As[lk + 1][lr] = a.y; As[lk + 2][lr] = a.z; As[lk + 3][lr] = a.w;
    Bs[lk + 0][lr] = bv.x; Bs[lk + 1][lr] = bv.y; Bs[lk + 2][lr] = bv.z; Bs[lk + 3][lr] = bv.w;
    __syncthreads();
#pragma unroll
    for (int kk = 0; kk < 16; ++kk) {
      float4 af = *(const float4*)(&As[kk][ty * 4]);
      float4 bf = *(const float4*)(&Bs[kk][tx * 4]);
      float av[4] = {af.x, af.y, af.z, af.w};
      float bb[4] = {bf.x, bf.y, bf.z, bf.w};
#pragma unroll
      for (int ii = 0; ii < 4; ++ii)
#pragma unroll
        for (int jj = 0; jj < 4; ++jj)
          acc[ii][jj] = fmaf(av[ii], bb[jj], acc[ii][jj]);
    }
    __syncthreads();
  }
  float4 bb4 = *(const float4*)(bias + tx * 4);
  float bb[4] = {bb4.x, bb4.y, bb4.z, bb4.w};
#pragma unroll
  for (int ii = 0; ii < 4; ++ii) {
    int row = m0 + ty * 4 + ii;
    int b = row >> 4, pos = row & 15;
    float* hp = h2 + (size_t)b * 1024 + pos;
#pragma unroll
    for (int jj = 0; jj < 4; ++jj)
      hp[(tx * 4 + jj) * 16] = fmaxf(acc[ii][jj] + bb[jj], 0.f);
  }
}

// ---------------- conv3 K-split partial (fp32, encoder precision) ----------
__global__ __launch_bounds__(256) void k_conv3p(const float* __restrict__ A,
    const float* __restrict__ w3, float* __restrict__ part) {
  __shared__ __align__(16) float As[16][68];
  __shared__ __align__(16) float Bs[16][68];
  int t = threadIdx.x;
  int m0 = blockIdx.x * 64, n0 = blockIdx.y * 64;
  int kb = blockIdx.z * 256;
  int tx = t & 15, ty = t >> 4;
  float acc[4][4] = {};
  int lr = t >> 2, lk = (t & 3) * 4;
  for (int k0 = kb; k0 < kb + 256; k0 += 16) {
    float4 a  = *(const float4*)(A  + (size_t)(m0 + lr) * 1024 + k0 + lk);
    float4 bv = *(const float4*)(w3 + (size_t)(n0 + lr) * 1024 + k0 + lk);
    As[lk + 0][lr] = a.x; As[lk + 1][lr] = a.y; As[lk + 2][lr] = a.z; As[lk + 3][lr] = a.w;
    Bs[lk + 0][lr] = bv.x; Bs[lk + 1][lr] = bv.y; Bs[lk + 2][lr] = bv.z; Bs[lk + 3][lr] = bv.w;
    __syncthreads();
#pragma unroll
    for (int kk = 0; kk < 16; ++kk) {
      float4 af = *(const float4*)(&As[kk][ty * 4]);
      float4 bf = *(const float4*)(&Bs[kk][tx * 4]);
      float av[4] = {af.x, af.y, af.z, af.w};
      float bb[4] = {bf.x, bf.y, bf.z, bf.w};
#pragma unroll
      for (int ii = 0; ii < 4; ++ii)
#pragma unroll
        for (int jj = 0; jj < 4; ++jj)
          acc[ii][jj] = fmaf(av[ii], bb[jj], acc[ii][jj]);
    }
    __syncthreads();
  }
  float* pc = part + (size_t)blockIdx.z * 1048576;
#pragma unroll
  for (int ii = 0; ii < 4; ++ii) {
    int row = m0 + ty * 4 + ii;
    *(float4*)(pc + (size_t)row * 256 + n0 + tx * 4) =
        make_float4(acc[ii][0], acc[ii][1], acc[ii][2], acc[ii][3]);
  }
}

__global__ __launch_bounds__(256) void k_c3red(const float* __restrict__ part,
    const float* __restrict__ b3, float* __restrict__ h) {
  int idx = blockIdx.x * 256 + threadIdx.x;
  int row = idx >> 6, c4 = (idx & 63) * 4;
  const float* p0 = part + (size_t)row * 256 + c4;
  float4 s  = *(const float4*)(p0);
  float4 s1 = *(const float4*)(p0 + 1048576);
  float4 s2 = *(const float4*)(p0 + 2097152);
  float4 s3 = *(const float4*)(p0 + 3145728);
  float4 bb = *(const float4*)(b3 + c4);
  float4 o;
  o.x = fmaxf(((s.x + s1.x) + s2.x) + s3.x + bb.x, 0.f);
  o.y = fmaxf(((s.y + s1.y) + s2.y) + s3.y + bb.y, 0.f);
  o.z = fmaxf(((s.z + s1.z) + s2.z) + s3.z + bb.z, 0.f);
  o.w = fmaxf(((s.w + s1.w) + s2.w) + s3.w + bb.w, 0.f);
  *(float4*)(h + (size_t)row * 256 + c4) = o;
}

// ---------------- headA: xzxu = relu(h (4096x256) @ [w_xz;w_xu]^T) (4096x64) fp32 ----
__global__ __launch_bounds__(256) void k_headA(const float* __restrict__ A,
    const float* __restrict__ w_xz, const float* __restrict__ w_xu,
    float* __restrict__ xzxu) {
  __shared__ __align__(16) float As[16][68];
  __shared__ __align__(16) float Bs[16][68];
  int t = threadIdx.x;
  int m0 = blockIdx.x * 64;
  int tx = t & 15, ty = t >> 4;
  float acc[4][4] = {};
  int lr = t >> 2, lk = (t & 3) * 4;
  const float* wr = (lr < 32) ? (w_xz + lr * 256) : (w_xu + (lr - 32) * 256);
  for (int k0 = 0; k0 < 256; k0 += 16) {
    float4 a  = *(const float4*)(A + (size_t)(m0 + lr) * 256 + k0 + lk);
    float4 bv = *(const float4*)(wr + k0 + lk);
    As[lk + 0][lr] = a.x; As[lk + 1][lr] = a.y; As[lk + 2][lr] = a.z; As[lk + 3][lr] = a.w;
    Bs[lk + 0][lr] = bv.x; Bs[lk + 1][lr] = bv.y; Bs[lk + 2][lr] = bv.z; Bs[lk + 3][lr] = bv.w;
    __syncthreads();
#pragma unroll
    for (int kk = 0; kk < 16; ++kk) {
      float4 af = *(const float4*)(&As[kk][ty * 4]);
      float4 bf = *(const float4*)(&Bs[kk][tx * 4]);
      float av[4] = {af.x, af.y, af.z, af.w};
      float bb[4] = {bf.x, bf.y, bf.z, bf.w};
#pragma unroll
      for (int ii = 0; ii < 4; ++ii)
#pragma unroll
        for (int jj = 0; jj < 4; ++jj)
          acc[ii][jj] = fmaf(av[ii], bb[jj], acc[ii][jj]);
    }
    __syncthreads();
  }
#pragma unroll
  for (int ii = 0; ii < 4; ++ii) {
    int row = m0 + ty * 4 + ii;
    float4 o;
    o.x = fmaxf(acc[ii][0], 0.f);
    o.y = fmaxf(acc[ii][1], 0.f);
    o.z = fmaxf(acc[ii][2], 0.f);
    o.w = fmaxf(acc[ii][3], 0.f);
    *(float4*)(xzxu + (size_t)row * 64 + tx * 4) = o;
  }
}

// ---------------- headB: small FCs + sampling + transform + x_hat (LDS bf16 tc) -----
// grid 256, 16 batches per block (staging amortized 4x)
__global__ __launch_bounds__(256) void k_headB(
    const float* __restrict__ xzxu,
    const float* __restrict__ w_label,
    const float* __restrict__ w_zd1, const float* __restrict__ w_zd2,
    const float* __restrict__ w_mu, const float* __restrict__ w_logvar,
    const float* __restrict__ tc_w, const float* __restrict__ tc_b,
    float* __restrict__ outp, unsigned short* __restrict__ xhb) {
  __shared__ __align__(16) unsigned short twL[16384];  // 32KB: tc_w bf16 [i][o][c]
  __shared__ __align__(16) unsigned short tbL[8192];   // 16KB: tc_b bf16 [i][o]
  __shared__ float xzs[4][32], xus[4][32];
  __shared__ float zls[4][10], gbs[4][10];
  __shared__ float mus[4][2], lvs[4][2], epss[4][2], uos[4][2];
  __shared__ float t1s[4][32], t2s[4][32];
  __shared__ int zhs[4];
  int t = threadIdx.x;
  int wv = t >> 6, l = t & 63;

  // stage tc_w (16384 f) + tc_b (8192 f) as bf16 -- once per block
  for (int v = t; v < 4096; v += 256) {
    float4 w4 = *(const float4*)(tc_w + (size_t)v * 4);
    unsigned short pk[4] = {f2b(w4.x), f2b(w4.y), f2b(w4.z), f2b(w4.w)};
    *(ushort4*)(twL + v * 4) = *(ushort4*)pk;
  }
  for (int v = t; v < 2048; v += 256) {
    float4 b4 = *(const float4*)(tc_b + (size_t)v * 4);
    unsigned short pk[4] = {f2b(b4.x), f2b(b4.y), f2b(b4.z), f2b(b4.w)};
    *(ushort4*)(tbL + v * 4) = *(ushort4*)pk;
  }

  for (int bi = 0; bi < 4; ++bi) {
    int b = blockIdx.x * 16 + bi * 4 + wv;
    {
      float v = xzxu[(size_t)b * 64 + l];
      if (l < 32) xzs[wv][l] = v; else xus[wv][l - 32] = v;
    }
    __syncthreads();

    if (l < 10) {                       // z_logit
      float acc = 0.f;
#pragma unroll
      for (int k = 0; k < 32; ++k) acc = fmaf(xzs[wv][k], w_label[l * 32 + k], acc);
      zls[wv][l] = acc;
      outp[OFF_ZL + (size_t)b * 10 + l] = acc;
    } else if (l < 12) {                // mu
      int d = l - 10;
      float acc = 0.f;
#pragma unroll
      for (int k = 0; k < 32; ++k) acc = fmaf(xus[wv][k], w_mu[d * 32 + k], acc);
      mus[wv][d] = acc;
      outp[OFF_MU + (size_t)b * 2 + d] = acc;
    } else if (l < 14) {                // logvar
      int d = l - 12;
      float acc = 0.f;
#pragma unroll
      for (int k = 0; k < 32; ++k) acc = fmaf(xus[wv][k], w_logvar[d * 32 + k], acc);
      lvs[wv][d] = acc;
      outp[OFF_LV + (size_t)b * 2 + d] = acc;
    }
    __syncthreads();

    if (l < 10) {                       // gumbel
      uint32_t kc0, kc1;
      threefry(0u, 42u, 0u, 0u, kc0, kc1);
      uint32_t bits = tf_bits32(kc0, kc1, (uint32_t)(b * 10 + l));
      float f = __uint_as_float((bits >> 9) | 0x3F800000u) - 1.0f;
      float u = fmaxf(f, 1.17549435e-38f);
      float g = -logf(-logf(u));
      gbs[wv][l] = zls[wv][l] + g;
    } else if (l < 12) {                // eps (normal)
      int d = l - 10;
      uint32_t ke0, ke1;
      threefry(0u, 42u, 0u, 1u, ke0, ke1);
      uint32_t bits = tf_bits32(ke0, ke1, (uint32_t)(b * 2 + d));
      float f = __uint_as_float((bits >> 9) | 0x3F800000u) - 1.0f;
      float u = fmaxf(f * 2.0f - 0.99999994f, -0.99999994f);
      epss[wv][d] = 1.41421356f * erfinv_xla(u);
    }
    __syncthreads();

    if (l == 0) {                       // argmax
      float best = gbs[wv][0];
      int bi2 = 0;
#pragma unroll
      for (int c = 1; c < 10; ++c) {
        float v = gbs[wv][c];
        if (v > best) { best = v; bi2 = c; }
      }
      zhs[wv] = bi2;
      outp[OFF_ZH + b] = (float)bi2;
    } else if (l < 3) {
      int d = l - 1;
      float sd = expf(0.5f * lvs[wv][d]);
      float uo = fmaf(epss[wv][d], sd, mus[wv][d]);
      uos[wv][d] = uo;
      outp[OFF_UO + (size_t)b * 2 + d] = uo;
    }
    __syncthreads();

    if (l < 32) {
      int zh = zhs[wv];
      float t1 = uos[wv][0] + w_zd1[l * 10 + zh];
      float t2 = uos[wv][1] + w_zd2[l * 10 + zh];
      t1s[wv][l] = t1; t2s[wv][l] = t2;
      outp[OFF_T1 + (size_t)b * 32 + l] = t1;
      outp[OFF_T2 + (size_t)b * 32 + l] = t2;
    }
    __syncthreads();

    {                                   // x_hat from LDS bf16 tc_w/tc_b
      float ax = 0.f, ay = 0.f, az = 0.f, aw = 0.f;
#pragma unroll 4
      for (int i = 0; i < 32; ++i) {
        float t1 = t1s[wv][i], t2 = t2s[wv][i];
        ushort4 wa = *(const ushort4*)(twL + i * 512 + l * 8);
        ushort4 wb = *(const ushort4*)(twL + i * 512 + l * 8 + 4);
        ushort4 tb = *(const ushort4*)(tbL + i * 256 + l * 4);
        float s;
        s = fmaf(t1, b2f(wa.x), fmaf(t2, b2f(wa.y), b2f(tb.x))); ax += fmaxf(s, 0.f);
        s = fmaf(t1, b2f(wa.z), fmaf(t2, b2f(wa.w), b2f(tb.y))); ay += fmaxf(s, 0.f);
        s = fmaf(t1, b2f(wb.x), fmaf(t2, b2f(wb.y), b2f(tb.z))); az += fmaxf(s, 0.f);
        s = fmaf(t1, b2f(wb.z), fmaf(t2, b2f(wb.w), b2f(tb.w))); aw += fmaxf(s, 0.f);
      }
      unsigned short pk[4] = {f2b(ax), f2b(ay), f2b(az), f2b(aw)};
      *(ushort4*)(xhb + (size_t)b * 256 + l * 4) = *(ushort4*)pk;
    }
    __syncthreads();
  }
}

// ---------------- dec3 MFMA: xh_bf16 (4096x256) @ W3t^T -> d3t bf16 (65536x64), relu
__global__ __launch_bounds__(256) void k_dec3m(const unsigned short* __restrict__ xhb,
    const unsigned short* __restrict__ w3t, const float* __restrict__ bias,
    unsigned short* __restrict__ d3t) {
  int t = threadIdx.x;
  int lane = t & 63, wv = t >> 6;
  int m0 = blockIdx.x * 64, n0 = blockIdx.y * 64;
  int l15 = lane & 15, g8 = (lane >> 4) * 8;
  const unsigned short* arow = xhb + (size_t)(m0 + wv * 16 + l15) * 256 + g8;
  const unsigned short* brow = w3t + (size_t)(n0 + l15) * 256 + g8;
  f32x4 acc[4] = {};
  for (int kb = 0; kb < 256; kb += 32) {
    bf16x8 af = *(const bf16x8*)(arow + kb);
#pragma unroll
    for (int ns = 0; ns < 4; ++ns) {
      bf16x8 bf = *(const bf16x8*)(brow + (size_t)ns * 4096 + kb);
      acc[ns] = __builtin_amdgcn_mfma_f32_16x16x32_bf16(af, bf, acc[ns], 0, 0, 0);
    }
  }
  int rbase = (lane >> 4) * 4;
#pragma unroll
  for (int ns = 0; ns < 4; ++ns) {
    int ncol = n0 + ns * 16 + l15;
    float bb = bias[ncol & 63];
#pragma unroll
    for (int r = 0; r < 4; ++r) {
      float v = fmaxf(acc[ns][r] + bb, 0.f);
      d3t[(size_t)(m0 + wv * 16 + rbase + r) * 1024 + ncol] = f2b(v);
    }
  }
}

// ---------------- dec2 MFMA + fused dec1 ----------------
__global__ __launch_bounds__(256) void k_dec2m(const unsigned short* __restrict__ d3t,
    const unsigned short* __restrict__ w2t, const float* __restrict__ b2,
    const float* __restrict__ w1, const float* __restrict__ b1,
    float* __restrict__ outp) {
  __shared__ unsigned short d2L[4][4096];
  __shared__ __align__(16) float w1s[256];
  __shared__ float b1s;
  int t = threadIdx.x;
  int lane = t & 63, wv = t >> 6;
  int m0 = blockIdx.x * 64;
  w1s[t] = w1[t];
  if (t == 0) b1s = b1[0];
  int l15 = lane & 15, g8 = (lane >> 4) * 8;
  const unsigned short* arow = d3t + (size_t)(m0 + wv * 16 + l15) * 64 + g8;
  bf16x8 af0 = *(const bf16x8*)(arow);
  bf16x8 af1 = *(const bf16x8*)(arow + 32);
  const unsigned short* brow = w2t + (size_t)l15 * 64 + g8;
  f32x4 acc[16] = {};
#pragma unroll
  for (int ns = 0; ns < 16; ++ns) {
    bf16x8 bf0 = *(const bf16x8*)(brow + (size_t)ns * 1024);
    bf16x8 bf1 = *(const bf16x8*)(brow + (size_t)ns * 1024 + 32);
    acc[ns] = __builtin_amdgcn_mfma_f32_16x16x32_bf16(af0, bf0, acc[ns], 0, 0, 0);
    acc[ns] = __builtin_amdgcn_mfma_f32_16x16x32_bf16(af1, bf1, acc[ns], 0, 0, 0);
  }
  int rbase = (lane >> 4) * 4;
  int pq_p = l15 >> 2, pq_q = l15 & 3;
#pragma unroll
  for (int ns = 0; ns < 16; ++ns) {
    float bb = b2[ns];
#pragma unroll
    for (int r = 0; r < 4; ++r) {
      int pos = rbase + r;
      float v = fmaxf(acc[ns][r] + bb, 0.f);
      d2L[wv][ns * 256 + ((pos >> 2) * 4 + pq_p) * 16 + (pos & 3) * 4 + pq_q] = f2b(v);
    }
  }
  __syncthreads();
  int bg0 = m0 >> 4;
  for (int c4 = 0; c4 < 16; ++c4) {
    int v = t + 256 * c4;
    int bp = v >> 10;
    int I = (v & 1023) >> 4;
    int jpix = v & 15;
    int ipix = I >> 2, pp = I & 3;
    const unsigned short* dl = &d2L[bp][ipix * 16 + jpix];
    float4 o = make_float4(b1s, b1s, b1s, b1s);
#pragma unroll
    for (int c = 0; c < 16; ++c) {
      float dv = b2f(dl[c * 256]);
      float4 wv4 = *(const float4*)(w1s + c * 16 + pp * 4);
      o.x = fmaf(dv, wv4.x, o.x);
      o.y = fmaf(dv, wv4.y, o.y);
      o.z = fmaf(dv, wv4.z, o.z);
      o.w = fmaf(dv, wv4.w, o.w);
    }
    *(float4*)(outp + (size_t)(bg0 + bp) * 4096 + I * 64 + jpix * 4) = o;
  }
}

extern "C" void kernel_launch(void* const* d_in, const int* in_sizes, int n_in,
                              void* d_out, int out_size, void* d_ws, size_t ws_size,
                              hipStream_t stream) {
  const float* x       = (const float*)d_in[0];
  const float* conv1_w = (const float*)d_in[3];
  const float* conv1_b = (const float*)d_in[4];
  const float* conv2_w = (const float*)d_in[5];
  const float* conv2_b = (const float*)d_in[6];
  const float* conv3_w = (const float*)d_in[7];
  const float* conv3_b = (const float*)d_in[8];
  const float* w_xz    = (const float*)d_in[9];
  const float* w_label = (const float*)d_in[10];
  const float* w_zd1   = (const float*)d_in[11];
  const float* w_zd2   = (const float*)d_in[12];
  const float* w_xu    = (const float*)d_in[13];
  const float* w_mu    = (const float*)d_in[14];
  const float* w_logvar= (const float*)d_in[15];
  const float* tc_w    = (const float*)d_in[16];
  const float* tc_b    = (const float*)d_in[17];
  const float* dec3_w  = (const float*)d_in[18];
  const float* dec3_b  = (const float*)d_in[19];
  const float* dec2_w  = (const float*)d_in[20];
  const float* dec2_b  = (const float*)d_in[21];
  const float* dec1_w  = (const float*)d_in[22];
  const float* dec1_b  = (const float*)d_in[23];

  float* out = (float*)d_out;
  float* ws  = (float*)d_ws;

  float* big = out + OFF_XL;                         // h1t -> conv3 partials -> final out
  float* h2  = ws;                                   // fp32 h2 [0 .. 4M)
  float* h   = ws + 4194304;                         // fp32 h  [4M .. 5.24M)
  unsigned short* d3t = (unsigned short*)ws;         // bf16 d3t reuses [0 .. 2M floats)
  unsigned short* xhb = (unsigned short*)(ws + 5242880);   // bf16 xh (0.5M float-slots)
  unsigned short* w3t = (unsigned short*)(ws + 5767168);   // bf16 W3t (128K float-slots)
  unsigned short* w2t = (unsigned short*)(ws + 5898240);   // bf16 W2t (8K float-slots)
  float* xzxu = ws + 5906432;                        // fp32 xzxu (256K floats)

  k_prep<<<136, 256, 0, stream>>>(dec3_w, dec2_w, w3t, w2t);
  k_conv1<<<B_TOT, 256, 0, stream>>>(x, conv1_w, conv1_b, big);
  k_conv2g<<<1024, 256, 0, stream>>>(big, conv2_w, conv2_b, h2);
  k_conv3p<<<dim3(64, 4, 4), 256, 0, stream>>>(h2, conv3_w, big);
  k_c3red<<<1024, 256, 0, stream>>>(big, conv3_b, h);
  k_headA<<<64, 256, 0, stream>>>(h, w_xz, w_xu, xzxu);
  k_headB<<<256, 256, 0, stream>>>(xzxu, w_label, w_zd1, w_zd2, w_mu,
                                   w_logvar, tc_w, tc_b, out, xhb);
  k_dec3m<<<dim3(64, 16), 256, 0, stream>>>(xhb, w3t, dec3_b, d3t);
  k_dec2m<<<1024, 256, 0, stream>>>(d3t, w2t, dec2_b, dec1_w, dec1_b, big);
}

// Round 9
// 191.232 us; speedup vs baseline: 1.2734x; 1.0426x over previous
//
#include <hip/hip_runtime.h>
#include <stdint.h>

#define B_TOT 4096

// ---- output offsets (floats) ----
#define OFF_ZL 0
#define OFF_ZH 40960
#define OFF_MU 45056
#define OFF_LV 53248
#define OFF_UO 61440
#define OFF_XL 69632
#define OFF_T1 16846848
#define OFF_T2 16977920

typedef __attribute__((ext_vector_type(8))) short bf16x8;
typedef __attribute__((ext_vector_type(4))) float f32x4;

// bf16 round-to-nearest-even from fp32 (finite values)
__device__ __forceinline__ unsigned short f2b(float f) {
  unsigned int u = __float_as_uint(f);
  return (unsigned short)((u + 0x7FFFu + ((u >> 16) & 1u)) >> 16);
}
__device__ __forceinline__ float b2f(unsigned short b) {
  return __uint_as_float(((unsigned int)b) << 16);
}

// ---------------- threefry2x32 (bit-exact JAX, partitionable path) ----------------
#define TF_ROUND(r) do { x0 += x1; x1 = (x1 << (r)) | (x1 >> (32-(r))); x1 ^= x0; } while(0)

__device__ __forceinline__ void threefry(uint32_t k0, uint32_t k1,
                                         uint32_t c0, uint32_t c1,
                                         uint32_t& o0, uint32_t& o1) {
  uint32_t ks2 = k0 ^ k1 ^ 0x1BD11BDAu;
  uint32_t x0 = c0 + k0, x1 = c1 + k1;
  TF_ROUND(13); TF_ROUND(15); TF_ROUND(26); TF_ROUND(6);
  x0 += k1;  x1 += ks2 + 1u;
  TF_ROUND(17); TF_ROUND(29); TF_ROUND(16); TF_ROUND(24);
  x0 += ks2; x1 += k0 + 2u;
  TF_ROUND(13); TF_ROUND(15); TF_ROUND(26); TF_ROUND(6);
  x0 += k0;  x1 += k1 + 3u;
  TF_ROUND(17); TF_ROUND(29); TF_ROUND(16); TF_ROUND(24);
  x0 += k1;  x1 += ks2 + 4u;
  TF_ROUND(13); TF_ROUND(15); TF_ROUND(26); TF_ROUND(6);
  x0 += ks2; x1 += k0 + 5u;
  o0 = x0; o1 = x1;
}

__device__ __forceinline__ uint32_t tf_bits32(uint32_t k0, uint32_t k1, uint32_t j) {
  uint32_t r0, r1;
  threefry(k0, k1, 0u, j, r0, r1);
  return r0 ^ r1;
}

// XLA ErfInv f32 (Giles polynomial)
__device__ __forceinline__ float erfinv_xla(float x) {
  float w = -log1pf(-x * x);
  float p;
  if (w < 5.0f) {
    w -= 2.5f;
    p = 2.81022636e-08f;
    p = fmaf(p, w, 3.43273939e-07f);
    p = fmaf(p, w, -3.5233877e-06f);
    p = fmaf(p, w, -4.39150654e-06f);
    p = fmaf(p, w, 0.00021858087f);
    p = fmaf(p, w, -0.00125372503f);
    p = fmaf(p, w, -0.00417768164f);
    p = fmaf(p, w, 0.246640727f);
    p = fmaf(p, w, 1.50140941f);
  } else {
    w = sqrtf(w) - 3.0f;
    p = -0.000200214257f;
    p = fmaf(p, w, 0.000100950558f);
    p = fmaf(p, w, 0.00134934322f);
    p = fmaf(p, w, -0.00367342844f);
    p = fmaf(p, w, 0.00573950773f);
    p = fmaf(p, w, -0.0076224613f);
    p = fmaf(p, w, 0.00943887047f);
    p = fmaf(p, w, 1.00167406f);
    p = fmaf(p, w, 2.83297682f);
  }
  return p * x;
}

// ---------------- prep: bf16-transpose decoder weights ----------------
__global__ __launch_bounds__(256) void k_prep(const float* __restrict__ w3,
    const float* __restrict__ w2, unsigned short* __restrict__ w3t,
    unsigned short* __restrict__ w2t) {
  int idx = blockIdx.x * 256 + threadIdx.x;
  unsigned short tmp[8];
  if (idx < 32768) {
    int np = idx >> 5, k0 = (idx & 31) * 8;
    int ic = np & 63, pos = np >> 6;
#pragma unroll
    for (int i = 0; i < 8; ++i)
      tmp[i] = f2b(w3[(size_t)(k0 + i) * 1024 + ic * 16 + pos]);
    *(bf16x8*)(w3t + (size_t)np * 256 + k0) = *(bf16x8*)tmp;
  } else if (idx < 32768 + 2048) {
    int j = idx - 32768;
    int n = j >> 3, k0 = (j & 7) * 8;
#pragma unroll
    for (int i = 0; i < 8; ++i)
      tmp[i] = f2b(w2[(size_t)(k0 + i) * 256 + n]);
    *(bf16x8*)(w2t + (size_t)n * 64 + k0) = *(bf16x8*)tmp;
  }
}

// ---------------- conv1: x (B,1,64,64) -> h1t (B, pos(16), ic*16+pq) im2col, relu ----
// LDS repack for fully-coalesced float4 global stores.
__global__ __launch_bounds__(256) void k_conv1(const float* __restrict__ x,
    const float* __restrict__ w, const float* __restrict__ bias,
    float* __restrict__ h1t) {
  __shared__ __align__(16) float ws[256];
  __shared__ float bs[16];
  __shared__ __align__(16) float ds[16 * 264];   // [pos][c], stride 264
  int b = blockIdx.x, t = threadIdx.x;
  ws[t] = w[t];
  if (t < 16) bs[t] = bias[t];
  __syncthreads();
  int i = t >> 4, j = t & 15;
  const float* xb = x + (size_t)b * 4096;
  float4 xv[4];
#pragma unroll
  for (int p = 0; p < 4; ++p)
    xv[p] = *(const float4*)(xb + (4 * i + p) * 64 + 4 * j);
  float acc[16];
#pragma unroll
  for (int oc = 0; oc < 16; ++oc) acc[oc] = bs[oc];
#pragma unroll
  for (int p = 0; p < 4; ++p) {
    float4 xp = xv[p];
#pragma unroll
    for (int oc = 0; oc < 16; ++oc) {
      float4 wv = *(const float4*)(ws + oc * 16 + p * 4);
      acc[oc] = fmaf(xp.x, wv.x, acc[oc]);
      acc[oc] = fmaf(xp.y, wv.y, acc[oc]);
      acc[oc] = fmaf(xp.z, wv.z, acc[oc]);
      acc[oc] = fmaf(xp.w, wv.w, acc[oc]);
    }
  }
  int pos = (i >> 2) * 4 + (j >> 2);
  int pq  = (i & 3) * 4 + (j & 3);
  float* dp = ds + pos * 264 + pq;
#pragma unroll
  for (int oc = 0; oc < 16; ++oc)
    dp[oc * 16] = fmaxf(acc[oc], 0.0f);
  __syncthreads();
  float* hb = h1t + (size_t)b * 4096;
#pragma unroll
  for (int pass = 0; pass < 4; ++pass) {
    int idx = pass * 1024 + t * 4;
    *(float4*)(hb + idx) = *(const float4*)(ds + (idx >> 8) * 264 + (idx & 255));
  }
}

// ---------------- conv2 as GEMM: h1t (65536x256) @ w2(64x256)^T -> h2 (b, oc*16+pos), relu
__global__ __launch_bounds__(256) void k_conv2g(const float* __restrict__ A,
    const float* __restrict__ Bw, const float* __restrict__ bias,
    float* __restrict__ h2) {
  __shared__ __align__(16) float As[16][68];
  __shared__ __align__(16) float Bs[16][68];
  int t = threadIdx.x;
  int m0 = blockIdx.x * 64;
  int tx = t & 15, ty = t >> 4;
  float acc[4][4] = {};
  int lr = t >> 2, lk = (t & 3) * 4;
  for (int k0 = 0; k0 < 256; k0 += 16) {
    float4 a  = *(const float4*)(A  + (size_t)(m0 + lr) * 256 + k0 + lk);
    float4 bv = *(const float4*)(Bw + (size_t)lr * 256 + k0 + lk);
    As[lk + 0][lr] = a.x; As[lk + 1][lr] = a.y; As[lk + 2][lr] = a.z; As[lk + 3][lr] = a.w;
    Bs[lk + 0][lr] = bv.x; Bs[lk + 1][lr] = bv.y; Bs[lk + 2][lr] = bv.z; Bs[lk + 3][lr] = bv.w;
    __syncthreads();
#pragma unroll
    for (int kk = 0; kk < 16; ++kk) {
      float4 af = *(const float4*)(&As[kk][ty * 4]);
      float4 bf = *(const float4*)(&Bs[kk][tx * 4]);
      float av[4] = {af.x, af.y, af.z, af.w};
      float bb[4] = {bf.x, bf.y, bf.z, bf.w};
#pragma unroll
      for (int ii = 0; ii < 4; ++ii)
#pragma unroll
        for (int jj = 0; jj < 4; ++jj)
          acc[ii][jj] = fmaf(av[ii], bb[jj], acc[ii][jj]);
    }
    __syncthreads();
  }
  float4 bb4 = *(const float4*)(bias + tx * 4);
  float bb[4] = {bb4.x, bb4.y, bb4.z, bb4.w};
#pragma unroll
  for (int ii = 0; ii < 4; ++ii) {
    int row = m0 + ty * 4 + ii;
    int b = row >> 4, pos = row & 15;
    float* hp = h2 + (size_t)b * 1024 + pos;
#pragma unroll
    for (int jj = 0; jj < 4; ++jj)
      hp[(tx * 4 + jj) * 16] = fmaxf(acc[ii][jj] + bb[jj], 0.f);
  }
}

// ---------------- conv3 K-split partial (fp32, encoder precision) ----------
__global__ __launch_bounds__(256) void k_conv3p(const float* __restrict__ A,
    const float* __restrict__ w3, float* __restrict__ part) {
  __shared__ __align__(16) float As[16][68];
  __shared__ __align__(16) float Bs[16][68];
  int t = threadIdx.x;
  int m0 = blockIdx.x * 64, n0 = blockIdx.y * 64;
  int kb = blockIdx.z * 256;
  int tx = t & 15, ty = t >> 4;
  float acc[4][4] = {};
  int lr = t >> 2, lk = (t & 3) * 4;
  for (int k0 = kb; k0 < kb + 256; k0 += 16) {
    float4 a  = *(const float4*)(A  + (size_t)(m0 + lr) * 1024 + k0 + lk);
    float4 bv = *(const float4*)(w3 + (size_t)(n0 + lr) * 1024 + k0 + lk);
    As[lk + 0][lr] = a.x; As[lk + 1][lr] = a.y; As[lk + 2][lr] = a.z; As[lk + 3][lr] = a.w;
    Bs[lk + 0][lr] = bv.x; Bs[lk + 1][lr] = bv.y; Bs[lk + 2][lr] = bv.z; Bs[lk + 3][lr] = bv.w;
    __syncthreads();
#pragma unroll
    for (int kk = 0; kk < 16; ++kk) {
      float4 af = *(const float4*)(&As[kk][ty * 4]);
      float4 bf = *(const float4*)(&Bs[kk][tx * 4]);
      float av[4] = {af.x, af.y, af.z, af.w};
      float bb[4] = {bf.x, bf.y, bf.z, bf.w};
#pragma unroll
      for (int ii = 0; ii < 4; ++ii)
#pragma unroll
        for (int jj = 0; jj < 4; ++jj)
          acc[ii][jj] = fmaf(av[ii], bb[jj], acc[ii][jj]);
    }
    __syncthreads();
  }
  float* pc = part + (size_t)blockIdx.z * 1048576;
#pragma unroll
  for (int ii = 0; ii < 4; ++ii) {
    int row = m0 + ty * 4 + ii;
    *(float4*)(pc + (size_t)row * 256 + n0 + tx * 4) =
        make_float4(acc[ii][0], acc[ii][1], acc[ii][2], acc[ii][3]);
  }
}

// ---------------- headA: fold c3red + FC. Reads 4 partials, h = relu(sum+bias),
// then xzxu = relu(h @ [w_xz;w_xu]^T). h values bit-identical to old c3red path.
__global__ __launch_bounds__(256) void k_headA(const float* __restrict__ part,
    const float* __restrict__ b3,
    const float* __restrict__ w_xz, const float* __restrict__ w_xu,
    float* __restrict__ xzxu) {
  __shared__ __align__(16) float As[16][68];
  __shared__ __align__(16) float Bs[16][68];
  int t = threadIdx.x;
  int m0 = blockIdx.x * 64;
  int tx = t & 15, ty = t >> 4;
  float acc[4][4] = {};
  int lr = t >> 2, lk = (t & 3) * 4;
  const float* wr = (lr < 32) ? (w_xz + lr * 256) : (w_xu + (lr - 32) * 256);
  for (int k0 = 0; k0 < 256; k0 += 16) {
    const float* p0 = part + (size_t)(m0 + lr) * 256 + k0 + lk;
    float4 s  = *(const float4*)(p0);
    float4 s1 = *(const float4*)(p0 + 1048576);
    float4 s2 = *(const float4*)(p0 + 2097152);
    float4 s3 = *(const float4*)(p0 + 3145728);
    float4 bb4 = *(const float4*)(b3 + k0 + lk);
    float4 a;
    a.x = fmaxf(((s.x + s1.x) + s2.x) + s3.x + bb4.x, 0.f);
    a.y = fmaxf(((s.y + s1.y) + s2.y) + s3.y + bb4.y, 0.f);
    a.z = fmaxf(((s.z + s1.z) + s2.z) + s3.z + bb4.z, 0.f);
    a.w = fmaxf(((s.w + s1.w) + s2.w) + s3.w + bb4.w, 0.f);
    float4 bv = *(const float4*)(wr + k0 + lk);
    As[lk + 0][lr] = a.x; As[lk + 1][lr] = a.y; As[lk + 2][lr] = a.z; As[lk + 3][lr] = a.w;
    Bs[lk + 0][lr] = bv.x; Bs[lk + 1][lr] = bv.y; Bs[lk + 2][lr] = bv.z; Bs[lk + 3][lr] = bv.w;
    __syncthreads();
#pragma unroll
    for (int kk = 0; kk < 16; ++kk) {
      float4 af = *(const float4*)(&As[kk][ty * 4]);
      float4 bf = *(const float4*)(&Bs[kk][tx * 4]);
      float av[4] = {af.x, af.y, af.z, af.w};
      float bb[4] = {bf.x, bf.y, bf.z, bf.w};
#pragma unroll
      for (int ii = 0; ii < 4; ++ii)
#pragma unroll
        for (int jj = 0; jj < 4; ++jj)
          acc[ii][jj] = fmaf(av[ii], bb[jj], acc[ii][jj]);
    }
    __syncthreads();
  }
#pragma unroll
  for (int ii = 0; ii < 4; ++ii) {
    int row = m0 + ty * 4 + ii;
    float4 o;
    o.x = fmaxf(acc[ii][0], 0.f);
    o.y = fmaxf(acc[ii][1], 0.f);
    o.z = fmaxf(acc[ii][2], 0.f);
    o.w = fmaxf(acc[ii][3], 0.f);
    *(float4*)(xzxu + (size_t)row * 64 + tx * 4) = o;
  }
}

// ---------------- headB: small FCs + sampling + transform + x_hat (LDS bf16 tc) -----
__global__ __launch_bounds__(256) void k_headB(
    const float* __restrict__ xzxu,
    const float* __restrict__ w_label,
    const float* __restrict__ w_zd1, const float* __restrict__ w_zd2,
    const float* __restrict__ w_mu, const float* __restrict__ w_logvar,
    const float* __restrict__ tc_w, const float* __restrict__ tc_b,
    float* __restrict__ outp, unsigned short* __restrict__ xhb) {
  __shared__ __align__(16) unsigned short twL[16384];  // 32KB: tc_w bf16 [i][o][c]
  __shared__ __align__(16) unsigned short tbL[8192];   // 16KB: tc_b bf16 [i][o]
  __shared__ float xzs[4][32], xus[4][32];
  __shared__ float zls[4][10], gbs[4][10];
  __shared__ float mus[4][2], lvs[4][2], epss[4][2], uos[4][2];
  __shared__ float t1s[4][32], t2s[4][32];
  __shared__ int zhs[4];
  int t = threadIdx.x;
  int wv = t >> 6, l = t & 63;
  int b = blockIdx.x * 4 + wv;

  for (int v = t; v < 4096; v += 256) {
    float4 w4 = *(const float4*)(tc_w + (size_t)v * 4);
    unsigned short pk[4] = {f2b(w4.x), f2b(w4.y), f2b(w4.z), f2b(w4.w)};
    *(ushort4*)(twL + v * 4) = *(ushort4*)pk;
  }
  for (int v = t; v < 2048; v += 256) {
    float4 b4 = *(const float4*)(tc_b + (size_t)v * 4);
    unsigned short pk[4] = {f2b(b4.x), f2b(b4.y), f2b(b4.z), f2b(b4.w)};
    *(ushort4*)(tbL + v * 4) = *(ushort4*)pk;
  }
  {
    float v = xzxu[(size_t)b * 64 + l];
    if (l < 32) xzs[wv][l] = v; else xus[wv][l - 32] = v;
  }
  __syncthreads();

  if (l < 10) {                       // z_logit
    float acc = 0.f;
#pragma unroll
    for (int k = 0; k < 32; ++k) acc = fmaf(xzs[wv][k], w_label[l * 32 + k], acc);
    zls[wv][l] = acc;
    outp[OFF_ZL + (size_t)b * 10 + l] = acc;
  } else if (l < 12) {                // mu
    int d = l - 10;
    float acc = 0.f;
#pragma unroll
    for (int k = 0; k < 32; ++k) acc = fmaf(xus[wv][k], w_mu[d * 32 + k], acc);
    mus[wv][d] = acc;
    outp[OFF_MU + (size_t)b * 2 + d] = acc;
  } else if (l < 14) {                // logvar
    int d = l - 12;
    float acc = 0.f;
#pragma unroll
    for (int k = 0; k < 32; ++k) acc = fmaf(xus[wv][k], w_logvar[d * 32 + k], acc);
    lvs[wv][d] = acc;
    outp[OFF_LV + (size_t)b * 2 + d] = acc;
  }
  __syncthreads();

  if (l < 10) {                       // gumbel
    uint32_t kc0, kc1;
    threefry(0u, 42u, 0u, 0u, kc0, kc1);
    uint32_t bits = tf_bits32(kc0, kc1, (uint32_t)(b * 10 + l));
    float f = __uint_as_float((bits >> 9) | 0x3F800000u) - 1.0f;
    float u = fmaxf(f, 1.17549435e-38f);
    float g = -logf(-logf(u));
    gbs[wv][l] = zls[wv][l] + g;
  } else if (l < 12) {                // eps (normal)
    int d = l - 10;
    uint32_t ke0, ke1;
    threefry(0u, 42u, 0u, 1u, ke0, ke1);
    uint32_t bits = tf_bits32(ke0, ke1, (uint32_t)(b * 2 + d));
    float f = __uint_as_float((bits >> 9) | 0x3F800000u) - 1.0f;
    float u = fmaxf(f * 2.0f - 0.99999994f, -0.99999994f);
    epss[wv][d] = 1.41421356f * erfinv_xla(u);
  }
  __syncthreads();

  if (l == 0) {                       // argmax
    float best = gbs[wv][0];
    int bi = 0;
#pragma unroll
    for (int c = 1; c < 10; ++c) {
      float v = gbs[wv][c];
      if (v > best) { best = v; bi = c; }
    }
    zhs[wv] = bi;
    outp[OFF_ZH + b] = (float)bi;
  } else if (l < 3) {
    int d = l - 1;
    float sd = expf(0.5f * lvs[wv][d]);
    float uo = fmaf(epss[wv][d], sd, mus[wv][d]);
    uos[wv][d] = uo;
    outp[OFF_UO + (size_t)b * 2 + d] = uo;
  }
  __syncthreads();

  if (l < 32) {
    int zh = zhs[wv];
    float t1 = uos[wv][0] + w_zd1[l * 10 + zh];
    float t2 = uos[wv][1] + w_zd2[l * 10 + zh];
    t1s[wv][l] = t1; t2s[wv][l] = t2;
    outp[OFF_T1 + (size_t)b * 32 + l] = t1;
    outp[OFF_T2 + (size_t)b * 32 + l] = t2;
  }
  __syncthreads();

  {                                   // x_hat from LDS bf16 tc_w/tc_b
    float ax = 0.f, ay = 0.f, az = 0.f, aw = 0.f;
#pragma unroll 4
    for (int i = 0; i < 32; ++i) {
      float t1 = t1s[wv][i], t2 = t2s[wv][i];
      ushort4 wa = *(const ushort4*)(twL + i * 512 + l * 8);
      ushort4 wb = *(const ushort4*)(twL + i * 512 + l * 8 + 4);
      ushort4 tb = *(const ushort4*)(tbL + i * 256 + l * 4);
      float s;
      s = fmaf(t1, b2f(wa.x), fmaf(t2, b2f(wa.y), b2f(tb.x))); ax += fmaxf(s, 0.f);
      s = fmaf(t1, b2f(wa.z), fmaf(t2, b2f(wa.w), b2f(tb.y))); ay += fmaxf(s, 0.f);
      s = fmaf(t1, b2f(wb.x), fmaf(t2, b2f(wb.y), b2f(tb.z))); az += fmaxf(s, 0.f);
      s = fmaf(t1, b2f(wb.z), fmaf(t2, b2f(wb.w), b2f(tb.w))); aw += fmaxf(s, 0.f);
    }
    unsigned short pk[4] = {f2b(ax), f2b(ay), f2b(az), f2b(aw)};
    *(ushort4*)(xhb + (size_t)b * 256 + l * 4) = *(ushort4*)pk;
  }
}

// ---------------- dec3 MFMA: xh_bf16 (4096x256) @ W3t^T -> d3t bf16, relu ----------
__global__ __launch_bounds__(256) void k_dec3m(const unsigned short* __restrict__ xhb,
    const unsigned short* __restrict__ w3t, const float* __restrict__ bias,
    unsigned short* __restrict__ d3t) {
  int t = threadIdx.x;
  int lane = t & 63, wv = t >> 6;
  int m0 = blockIdx.x * 64, n0 = blockIdx.y * 64;
  int l15 = lane & 15, g8 = (lane >> 4) * 8;
  const unsigned short* arow = xhb + (size_t)(m0 + wv * 16 + l15) * 256 + g8;
  const unsigned short* brow = w3t + (size_t)(n0 + l15) * 256 + g8;
  f32x4 acc[4] = {};
  for (int kb = 0; kb < 256; kb += 32) {
    bf16x8 af = *(const bf16x8*)(arow + kb);
#pragma unroll
    for (int ns = 0; ns < 4; ++ns) {
      bf16x8 bf = *(const bf16x8*)(brow + (size_t)ns * 4096 + kb);
      acc[ns] = __builtin_amdgcn_mfma_f32_16x16x32_bf16(af, bf, acc[ns], 0, 0, 0);
    }
  }
  int rbase = (lane >> 4) * 4;
#pragma unroll
  for (int ns = 0; ns < 4; ++ns) {
    int ncol = n0 + ns * 16 + l15;
    float bb = bias[ncol & 63];
#pragma unroll
    for (int r = 0; r < 4; ++r) {
      float v = fmaxf(acc[ns][r] + bb, 0.f);
      d3t[(size_t)(m0 + wv * 16 + rbase + r) * 1024 + ncol] = f2b(v);
    }
  }
}

// ---------------- dec2 MFMA + fused dec1 ----------------
__global__ __launch_bounds__(256) void k_dec2m(const unsigned short* __restrict__ d3t,
    const unsigned short* __restrict__ w2t, const float* __restrict__ b2,
    const float* __restrict__ w1, const float* __restrict__ b1,
    float* __restrict__ outp) {
  __shared__ unsigned short d2L[4][4096];
  __shared__ __align__(16) float w1s[256];
  __shared__ float b1s;
  int t = threadIdx.x;
  int lane = t & 63, wv = t >> 6;
  int m0 = blockIdx.x * 64;
  w1s[t] = w1[t];
  if (t == 0) b1s = b1[0];
  int l15 = lane & 15, g8 = (lane >> 4) * 8;
  const unsigned short* arow = d3t + (size_t)(m0 + wv * 16 + l15) * 64 + g8;
  bf16x8 af0 = *(const bf16x8*)(arow);
  bf16x8 af1 = *(const bf16x8*)(arow + 32);
  const unsigned short* brow = w2t + (size_t)l15 * 64 + g8;
  f32x4 acc[16] = {};
#pragma unroll
  for (int ns = 0; ns < 16; ++ns) {
    bf16x8 bf0 = *(const bf16x8*)(brow + (size_t)ns * 1024);
    bf16x8 bf1 = *(const bf16x8*)(brow + (size_t)ns * 1024 + 32);
    acc[ns] = __builtin_amdgcn_mfma_f32_16x16x32_bf16(af0, bf0, acc[ns], 0, 0, 0);
    acc[ns] = __builtin_amdgcn_mfma_f32_16x16x32_bf16(af1, bf1, acc[ns], 0, 0, 0);
  }
  int rbase = (lane >> 4) * 4;
  int pq_p = l15 >> 2, pq_q = l15 & 3;
#pragma unroll
  for (int ns = 0; ns < 16; ++ns) {
    float bb = b2[ns];
#pragma unroll
    for (int r = 0; r < 4; ++r) {
      int pos = rbase + r;
      float v = fmaxf(acc[ns][r] + bb, 0.f);
      d2L[wv][ns * 256 + ((pos >> 2) * 4 + pq_p) * 16 + (pos & 3) * 4 + pq_q] = f2b(v);
    }
  }
  __syncthreads();
  int bg0 = m0 >> 4;
  for (int c4 = 0; c4 < 16; ++c4) {
    int v = t + 256 * c4;
    int bp = v >> 10;
    int I = (v & 1023) >> 4;
    int jpix = v & 15;
    int ipix = I >> 2, pp = I & 3;
    const unsigned short* dl = &d2L[bp][ipix * 16 + jpix];
    float4 o = make_float4(b1s, b1s, b1s, b1s);
#pragma unroll
    for (int c = 0; c < 16; ++c) {
      float dv = b2f(dl[c * 256]);
      float4 wv4 = *(const float4*)(w1s + c * 16 + pp * 4);
      o.x = fmaf(dv, wv4.x, o.x);
      o.y = fmaf(dv, wv4.y, o.y);
      o.z = fmaf(dv, wv4.z, o.z);
      o.w = fmaf(dv, wv4.w, o.w);
    }
    *(float4*)(outp + (size_t)(bg0 + bp) * 4096 + I * 64 + jpix * 4) = o;
  }
}

extern "C" void kernel_launch(void* const* d_in, const int* in_sizes, int n_in,
                              void* d_out, int out_size, void* d_ws, size_t ws_size,
                              hipStream_t stream) {
  const float* x       = (const float*)d_in[0];
  const float* conv1_w = (const float*)d_in[3];
  const float* conv1_b = (const float*)d_in[4];
  const float* conv2_w = (const float*)d_in[5];
  const float* conv2_b = (const float*)d_in[6];
  const float* conv3_w = (const float*)d_in[7];
  const float* conv3_b = (const float*)d_in[8];
  const float* w_xz    = (const float*)d_in[9];
  const float* w_label = (const float*)d_in[10];
  const float* w_zd1   = (const float*)d_in[11];
  const float* w_zd2   = (const float*)d_in[12];
  const float* w_xu    = (const float*)d_in[13];
  const float* w_mu    = (const float*)d_in[14];
  const float* w_logvar= (const float*)d_in[15];
  const float* tc_w    = (const float*)d_in[16];
  const float* tc_b    = (const float*)d_in[17];
  const float* dec3_w  = (const float*)d_in[18];
  const float* dec3_b  = (const float*)d_in[19];
  const float* dec2_w  = (const float*)d_in[20];
  const float* dec2_b  = (const float*)d_in[21];
  const float* dec1_w  = (const float*)d_in[22];
  const float* dec1_b  = (const float*)d_in[23];

  float* out = (float*)d_out;
  float* ws  = (float*)d_ws;

  float* big = out + OFF_XL;                         // h1t -> conv3 partials -> final out
  float* h2  = ws;                                   // fp32 h2 [0 .. 4M)
  unsigned short* d3t = (unsigned short*)ws;         // bf16 d3t reuses [0 .. 2M floats)
  unsigned short* xhb = (unsigned short*)(ws + 5242880);   // bf16 xh (0.5M float-slots)
  unsigned short* w3t = (unsigned short*)(ws + 5767168);   // bf16 W3t (128K float-slots)
  unsigned short* w2t = (unsigned short*)(ws + 5898240);   // bf16 W2t (8K float-slots)
  float* xzxu = ws + 5906432;                        // fp32 xzxu (256K floats)

  k_prep<<<136, 256, 0, stream>>>(dec3_w, dec2_w, w3t, w2t);
  k_conv1<<<B_TOT, 256, 0, stream>>>(x, conv1_w, conv1_b, big);
  k_conv2g<<<1024, 256, 0, stream>>>(big, conv2_w, conv2_b, h2);
  k_conv3p<<<dim3(64, 4, 4), 256, 0, stream>>>(h2, conv3_w, big);
  k_headA<<<64, 256, 0, stream>>>(big, conv3_b, w_xz, w_xu, xzxu);
  k_headB<<<B_TOT / 4, 256, 0, stream>>>(xzxu, w_label, w_zd1, w_zd2, w_mu,
                                         w_logvar, tc_w, tc_b, out, xhb);
  k_dec3m<<<dim3(64, 16), 256, 0, stream>>>(xhb, w3t, dec3_b, d3t);
  k_dec2m<<<1024, 256, 0, stream>>>(d3t, w2t, dec2_b, dec1_w, dec1_b, big);
}

// Round 10
// 187.936 us; speedup vs baseline: 1.2958x; 1.0175x over previous
//
#include <hip/hip_runtime.h>
#include <stdint.h>

#define B_TOT 4096

// ---- output offsets (floats) ----
#define OFF_ZL 0
#define OFF_ZH 40960
#define OFF_MU 45056
#define OFF_LV 53248
#define OFF_UO 61440
#define OFF_XL 69632
#define OFF_T1 16846848
#define OFF_T2 16977920

typedef __attribute__((ext_vector_type(8))) short bf16x8;
typedef __attribute__((ext_vector_type(4))) float f32x4;

__device__ __forceinline__ unsigned short f2b(float f) {
  unsigned int u = __float_as_uint(f);
  return (unsigned short)((u + 0x7FFFu + ((u >> 16) & 1u)) >> 16);
}
__device__ __forceinline__ float b2f(unsigned short b) {
  return __uint_as_float(((unsigned int)b) << 16);
}

// ---------------- threefry2x32 (bit-exact JAX, partitionable path) ----------------
#define TF_ROUND(r) do { x0 += x1; x1 = (x1 << (r)) | (x1 >> (32-(r))); x1 ^= x0; } while(0)

__device__ __forceinline__ void threefry(uint32_t k0, uint32_t k1,
                                         uint32_t c0, uint32_t c1,
                                         uint32_t& o0, uint32_t& o1) {
  uint32_t ks2 = k0 ^ k1 ^ 0x1BD11BDAu;
  uint32_t x0 = c0 + k0, x1 = c1 + k1;
  TF_ROUND(13); TF_ROUND(15); TF_ROUND(26); TF_ROUND(6);
  x0 += k1;  x1 += ks2 + 1u;
  TF_ROUND(17); TF_ROUND(29); TF_ROUND(16); TF_ROUND(24);
  x0 += ks2; x1 += k0 + 2u;
  TF_ROUND(13); TF_ROUND(15); TF_ROUND(26); TF_ROUND(6);
  x0 += k0;  x1 += k1 + 3u;
  TF_ROUND(17); TF_ROUND(29); TF_ROUND(16); TF_ROUND(24);
  x0 += k1;  x1 += ks2 + 4u;
  TF_ROUND(13); TF_ROUND(15); TF_ROUND(26); TF_ROUND(6);
  x0 += ks2; x1 += k0 + 5u;
  o0 = x0; o1 = x1;
}

__device__ __forceinline__ uint32_t tf_bits32(uint32_t k0, uint32_t k1, uint32_t j) {
  uint32_t r0, r1;
  threefry(k0, k1, 0u, j, r0, r1);
  return r0 ^ r1;
}

// XLA ErfInv f32 (Giles polynomial)
__device__ __forceinline__ float erfinv_xla(float x) {
  float w = -log1pf(-x * x);
  float p;
  if (w < 5.0f) {
    w -= 2.5f;
    p = 2.81022636e-08f;
    p = fmaf(p, w, 3.43273939e-07f);
    p = fmaf(p, w, -3.5233877e-06f);
    p = fmaf(p, w, -4.39150654e-06f);
    p = fmaf(p, w, 0.00021858087f);
    p = fmaf(p, w, -0.00125372503f);
    p = fmaf(p, w, -0.00417768164f);
    p = fmaf(p, w, 0.246640727f);
    p = fmaf(p, w, 1.50140941f);
  } else {
    w = sqrtf(w) - 3.0f;
    p = -0.000200214257f;
    p = fmaf(p, w, 0.000100950558f);
    p = fmaf(p, w, 0.00134934322f);
    p = fmaf(p, w, -0.00367342844f);
    p = fmaf(p, w, 0.00573950773f);
    p = fmaf(p, w, -0.0076224613f);
    p = fmaf(p, w, 0.00943887047f);
    p = fmaf(p, w, 1.00167406f);
    p = fmaf(p, w, 2.83297682f);
  }
  return p * x;
}

// ---------------- prep: bf16-transpose decoder weights ----------------
__global__ __launch_bounds__(256) void k_prep(const float* __restrict__ w3,
    const float* __restrict__ w2, unsigned short* __restrict__ w3t,
    unsigned short* __restrict__ w2t) {
  int idx = blockIdx.x * 256 + threadIdx.x;
  unsigned short tmp[8];
  if (idx < 32768) {
    int np = idx >> 5, k0 = (idx & 31) * 8;
    int ic = np & 63, pos = np >> 6;
#pragma unroll
    for (int i = 0; i < 8; ++i)
      tmp[i] = f2b(w3[(size_t)(k0 + i) * 1024 + ic * 16 + pos]);
    *(bf16x8*)(w3t + (size_t)np * 256 + k0) = *(bf16x8*)tmp;
  } else if (idx < 32768 + 2048) {
    int j = idx - 32768;
    int n = j >> 3, k0 = (j & 7) * 8;
#pragma unroll
    for (int i = 0; i < 8; ++i)
      tmp[i] = f2b(w2[(size_t)(k0 + i) * 256 + n]);
    *(bf16x8*)(w2t + (size_t)n * 64 + k0) = *(bf16x8*)tmp;
  }
}

// ---------------- conv1: x (B,1,64,64) -> h1t im2col, relu (coalesced stores) ------
__global__ __launch_bounds__(256) void k_conv1(const float* __restrict__ x,
    const float* __restrict__ w, const float* __restrict__ bias,
    float* __restrict__ h1t) {
  __shared__ __align__(16) float ws[256];
  __shared__ float bs[16];
  __shared__ __align__(16) float ds[16 * 264];
  int b = blockIdx.x, t = threadIdx.x;
  ws[t] = w[t];
  if (t < 16) bs[t] = bias[t];
  __syncthreads();
  int i = t >> 4, j = t & 15;
  const float* xb = x + (size_t)b * 4096;
  float4 xv[4];
#pragma unroll
  for (int p = 0; p < 4; ++p)
    xv[p] = *(const float4*)(xb + (4 * i + p) * 64 + 4 * j);
  float acc[16];
#pragma unroll
  for (int oc = 0; oc < 16; ++oc) acc[oc] = bs[oc];
#pragma unroll
  for (int p = 0; p < 4; ++p) {
    float4 xp = xv[p];
#pragma unroll
    for (int oc = 0; oc < 16; ++oc) {
      float4 wv = *(const float4*)(ws + oc * 16 + p * 4);
      acc[oc] = fmaf(xp.x, wv.x, acc[oc]);
      acc[oc] = fmaf(xp.y, wv.y, acc[oc]);
      acc[oc] = fmaf(xp.z, wv.z, acc[oc]);
      acc[oc] = fmaf(xp.w, wv.w, acc[oc]);
    }
  }
  int pos = (i >> 2) * 4 + (j >> 2);
  int pq  = (i & 3) * 4 + (j & 3);
  float* dp = ds + pos * 264 + pq;
#pragma unroll
  for (int oc = 0; oc < 16; ++oc)
    dp[oc * 16] = fmaxf(acc[oc], 0.0f);
  __syncthreads();
  float* hb = h1t + (size_t)b * 4096;
#pragma unroll
  for (int pass = 0; pass < 4; ++pass) {
    int idx = pass * 1024 + t * 4;
    *(float4*)(hb + idx) = *(const float4*)(ds + (idx >> 8) * 264 + (idx & 255));
  }
}

// ---------------- conv2 GEMM, M-tile 128: h1t (65536x256) @ w2^T -> h2, relu -------
// K-order bit-identical (k = 0..255 sequential per output).
__global__ __launch_bounds__(256) void k_conv2g(const float* __restrict__ A,
    const float* __restrict__ Bw, const float* __restrict__ bias,
    float* __restrict__ h2) {
  __shared__ __align__(16) float As[16][136];
  __shared__ __align__(16) float Bs[16][68];
  int t = threadIdx.x;
  int m0 = blockIdx.x * 128;
  int tx = t & 15, ty = t >> 4;
  float acc[8][4] = {};
  int lrA = t >> 1, lkA = (t & 1) * 8;
  int lrB = t >> 2, lkB = (t & 3) * 4;
  for (int k0 = 0; k0 < 256; k0 += 16) {
    const float* ap = A + (size_t)(m0 + lrA) * 256 + k0 + lkA;
    float4 a0 = *(const float4*)(ap);
    float4 a1 = *(const float4*)(ap + 4);
    float4 bv = *(const float4*)(Bw + (size_t)lrB * 256 + k0 + lkB);
    As[lkA + 0][lrA] = a0.x; As[lkA + 1][lrA] = a0.y;
    As[lkA + 2][lrA] = a0.z; As[lkA + 3][lrA] = a0.w;
    As[lkA + 4][lrA] = a1.x; As[lkA + 5][lrA] = a1.y;
    As[lkA + 6][lrA] = a1.z; As[lkA + 7][lrA] = a1.w;
    Bs[lkB + 0][lrB] = bv.x; Bs[lkB + 1][lrB] = bv.y;
    Bs[lkB + 2][lrB] = bv.z; Bs[lkB + 3][lrB] = bv.w;
    __syncthreads();
#pragma unroll
    for (int kk = 0; kk < 16; ++kk) {
      float4 af0 = *(const float4*)(&As[kk][ty * 8]);
      float4 af1 = *(const float4*)(&As[kk][ty * 8 + 4]);
      float4 bf  = *(const float4*)(&Bs[kk][tx * 4]);
      float av[8] = {af0.x, af0.y, af0.z, af0.w, af1.x, af1.y, af1.z, af1.w};
      float bw[4] = {bf.x, bf.y, bf.z, bf.w};
#pragma unroll
      for (int ii = 0; ii < 8; ++ii)
#pragma unroll
        for (int jj = 0; jj < 4; ++jj)
          acc[ii][jj] = fmaf(av[ii], bw[jj], acc[ii][jj]);
    }
    __syncthreads();
  }
  float4 bb4 = *(const float4*)(bias + tx * 4);
  float bb[4] = {bb4.x, bb4.y, bb4.z, bb4.w};
#pragma unroll
  for (int ii = 0; ii < 8; ++ii) {
    int row = m0 + ty * 8 + ii;
    int b = row >> 4, pos = row & 15;
    float* hp = h2 + (size_t)b * 1024 + pos;
#pragma unroll
    for (int jj = 0; jj < 4; ++jj)
      hp[(tx * 4 + jj) * 16] = fmaxf(acc[ii][jj] + bb[jj], 0.f);
  }
}

// ---------------- conv3 K-split partial, M-tile 128 (fp32) ----------
// grid (32, 4, 4): x=M-tile(128), y=N-tile(64), z=K-chunk(256).
__global__ __launch_bounds__(256) void k_conv3p(const float* __restrict__ A,
    const float* __restrict__ w3, float* __restrict__ part) {
  __shared__ __align__(16) float As[16][136];
  __shared__ __align__(16) float Bs[16][68];
  int t = threadIdx.x;
  int m0 = blockIdx.x * 128, n0 = blockIdx.y * 64;
  int kb = blockIdx.z * 256;
  int tx = t & 15, ty = t >> 4;
  float acc[8][4] = {};
  int lrA = t >> 1, lkA = (t & 1) * 8;
  int lrB = t >> 2, lkB = (t & 3) * 4;
  for (int k0 = kb; k0 < kb + 256; k0 += 16) {
    const float* ap = A + (size_t)(m0 + lrA) * 1024 + k0 + lkA;
    float4 a0 = *(const float4*)(ap);
    float4 a1 = *(const float4*)(ap + 4);
    float4 bv = *(const float4*)(w3 + (size_t)(n0 + lrB) * 1024 + k0 + lkB);
    As[lkA + 0][lrA] = a0.x; As[lkA + 1][lrA] = a0.y;
    As[lkA + 2][lrA] = a0.z; As[lkA + 3][lrA] = a0.w;
    As[lkA + 4][lrA] = a1.x; As[lkA + 5][lrA] = a1.y;
    As[lkA + 6][lrA] = a1.z; As[lkA + 7][lrA] = a1.w;
    Bs[lkB + 0][lrB] = bv.x; Bs[lkB + 1][lrB] = bv.y;
    Bs[lkB + 2][lrB] = bv.z; Bs[lkB + 3][lrB] = bv.w;
    __syncthreads();
#pragma unroll
    for (int kk = 0; kk < 16; ++kk) {
      float4 af0 = *(const float4*)(&As[kk][ty * 8]);
      float4 af1 = *(const float4*)(&As[kk][ty * 8 + 4]);
      float4 bf  = *(const float4*)(&Bs[kk][tx * 4]);
      float av[8] = {af0.x, af0.y, af0.z, af0.w, af1.x, af1.y, af1.z, af1.w};
      float bw[4] = {bf.x, bf.y, bf.z, bf.w};
#pragma unroll
      for (int ii = 0; ii < 8; ++ii)
#pragma unroll
        for (int jj = 0; jj < 4; ++jj)
          acc[ii][jj] = fmaf(av[ii], bw[jj], acc[ii][jj]);
    }
    __syncthreads();
  }
  float* pc = part + (size_t)blockIdx.z * 1048576;
#pragma unroll
  for (int ii = 0; ii < 8; ++ii) {
    int row = m0 + ty * 8 + ii;
    *(float4*)(pc + (size_t)row * 256 + n0 + tx * 4) =
        make_float4(acc[ii][0], acc[ii][1], acc[ii][2], acc[ii][3]);
  }
}

// ---------------- headA: fold c3red + FC (h bit-identical to c3red path) -----------
__global__ __launch_bounds__(256) void k_headA(const float* __restrict__ part,
    const float* __restrict__ b3,
    const float* __restrict__ w_xz, const float* __restrict__ w_xu,
    float* __restrict__ xzxu) {
  __shared__ __align__(16) float As[16][68];
  __shared__ __align__(16) float Bs[16][68];
  int t = threadIdx.x;
  int m0 = blockIdx.x * 64;
  int tx = t & 15, ty = t >> 4;
  float acc[4][4] = {};
  int lr = t >> 2, lk = (t & 3) * 4;
  const float* wr = (lr < 32) ? (w_xz + lr * 256) : (w_xu + (lr - 32) * 256);
  for (int k0 = 0; k0 < 256; k0 += 16) {
    const float* p0 = part + (size_t)(m0 + lr) * 256 + k0 + lk;
    float4 s  = *(const float4*)(p0);
    float4 s1 = *(const float4*)(p0 + 1048576);
    float4 s2 = *(const float4*)(p0 + 2097152);
    float4 s3 = *(const float4*)(p0 + 3145728);
    float4 bb4 = *(const float4*)(b3 + k0 + lk);
    float4 a;
    a.x = fmaxf(((s.x + s1.x) + s2.x) + s3.x + bb4.x, 0.f);
    a.y = fmaxf(((s.y + s1.y) + s2.y) + s3.y + bb4.y, 0.f);
    a.z = fmaxf(((s.z + s1.z) + s2.z) + s3.z + bb4.z, 0.f);
    a.w = fmaxf(((s.w + s1.w) + s2.w) + s3.w + bb4.w, 0.f);
    float4 bv = *(const float4*)(wr + k0 + lk);
    As[lk + 0][lr] = a.x; As[lk + 1][lr] = a.y; As[lk + 2][lr] = a.z; As[lk + 3][lr] = a.w;
    Bs[lk + 0][lr] = bv.x; Bs[lk + 1][lr] = bv.y; Bs[lk + 2][lr] = bv.z; Bs[lk + 3][lr] = bv.w;
    __syncthreads();
#pragma unroll
    for (int kk = 0; kk < 16; ++kk) {
      float4 af = *(const float4*)(&As[kk][ty * 4]);
      float4 bf = *(const float4*)(&Bs[kk][tx * 4]);
      float av[4] = {af.x, af.y, af.z, af.w};
      float bb[4] = {bf.x, bf.y, bf.z, bf.w};
#pragma unroll
      for (int ii = 0; ii < 4; ++ii)
#pragma unroll
        for (int jj = 0; jj < 4; ++jj)
          acc[ii][jj] = fmaf(av[ii], bb[jj], acc[ii][jj]);
    }
    __syncthreads();
  }
#pragma unroll
  for (int ii = 0; ii < 4; ++ii) {
    int row = m0 + ty * 4 + ii;
    float4 o;
    o.x = fmaxf(acc[ii][0], 0.f);
    o.y = fmaxf(acc[ii][1], 0.f);
    o.z = fmaxf(acc[ii][2], 0.f);
    o.w = fmaxf(acc[ii][3], 0.f);
    *(float4*)(xzxu + (size_t)row * 64 + tx * 4) = o;
  }
}

// ---------------- headB: small FCs + sampling + transform + x_hat ----------------
__global__ __launch_bounds__(256) void k_headB(
    const float* __restrict__ xzxu,
    const float* __restrict__ w_label,
    const float* __restrict__ w_zd1, const float* __restrict__ w_zd2,
    const float* __restrict__ w_mu, const float* __restrict__ w_logvar,
    const float* __restrict__ tc_w, const float* __restrict__ tc_b,
    float* __restrict__ outp, unsigned short* __restrict__ xhb) {
  __shared__ __align__(16) unsigned short twL[16384];
  __shared__ __align__(16) unsigned short tbL[8192];
  __shared__ float xzs[4][32], xus[4][32];
  __shared__ float zls[4][10], gbs[4][10];
  __shared__ float mus[4][2], lvs[4][2], epss[4][2], uos[4][2];
  __shared__ float t1s[4][32], t2s[4][32];
  __shared__ int zhs[4];
  int t = threadIdx.x;
  int wv = t >> 6, l = t & 63;
  int b = blockIdx.x * 4 + wv;

  for (int v = t; v < 4096; v += 256) {
    float4 w4 = *(const float4*)(tc_w + (size_t)v * 4);
    unsigned short pk[4] = {f2b(w4.x), f2b(w4.y), f2b(w4.z), f2b(w4.w)};
    *(ushort4*)(twL + v * 4) = *(ushort4*)pk;
  }
  for (int v = t; v < 2048; v += 256) {
    float4 b4 = *(const float4*)(tc_b + (size_t)v * 4);
    unsigned short pk[4] = {f2b(b4.x), f2b(b4.y), f2b(b4.z), f2b(b4.w)};
    *(ushort4*)(tbL + v * 4) = *(ushort4*)pk;
  }
  {
    float v = xzxu[(size_t)b * 64 + l];
    if (l < 32) xzs[wv][l] = v; else xus[wv][l - 32] = v;
  }
  __syncthreads();

  if (l < 10) {                       // z_logit
    float acc = 0.f;
#pragma unroll
    for (int k = 0; k < 32; ++k) acc = fmaf(xzs[wv][k], w_label[l * 32 + k], acc);
    zls[wv][l] = acc;
    outp[OFF_ZL + (size_t)b * 10 + l] = acc;
  } else if (l < 12) {                // mu
    int d = l - 10;
    float acc = 0.f;
#pragma unroll
    for (int k = 0; k < 32; ++k) acc = fmaf(xus[wv][k], w_mu[d * 32 + k], acc);
    mus[wv][d] = acc;
    outp[OFF_MU + (size_t)b * 2 + d] = acc;
  } else if (l < 14) {                // logvar
    int d = l - 12;
    float acc = 0.f;
#pragma unroll
    for (int k = 0; k < 32; ++k) acc = fmaf(xus[wv][k], w_logvar[d * 32 + k], acc);
    lvs[wv][d] = acc;
    outp[OFF_LV + (size_t)b * 2 + d] = acc;
  }
  __syncthreads();

  if (l < 10) {                       // gumbel
    uint32_t kc0, kc1;
    threefry(0u, 42u, 0u, 0u, kc0, kc1);
    uint32_t bits = tf_bits32(kc0, kc1, (uint32_t)(b * 10 + l));
    float f = __uint_as_float((bits >> 9) | 0x3F800000u) - 1.0f;
    float u = fmaxf(f, 1.17549435e-38f);
    float g = -logf(-logf(u));
    gbs[wv][l] = zls[wv][l] + g;
  } else if (l < 12) {                // eps (normal)
    int d = l - 10;
    uint32_t ke0, ke1;
    threefry(0u, 42u, 0u, 1u, ke0, ke1);
    uint32_t bits = tf_bits32(ke0, ke1, (uint32_t)(b * 2 + d));
    float f = __uint_as_float((bits >> 9) | 0x3F800000u) - 1.0f;
    float u = fmaxf(f * 2.0f - 0.99999994f, -0.99999994f);
    epss[wv][d] = 1.41421356f * erfinv_xla(u);
  }
  __syncthreads();

  if (l == 0) {                       // argmax
    float best = gbs[wv][0];
    int bi = 0;
#pragma unroll
    for (int c = 1; c < 10; ++c) {
      float v = gbs[wv][c];
      if (v > best) { best = v; bi = c; }
    }
    zhs[wv] = bi;
    outp[OFF_ZH + b] = (float)bi;
  } else if (l < 3) {
    int d = l - 1;
    float sd = expf(0.5f * lvs[wv][d]);
    float uo = fmaf(epss[wv][d], sd, mus[wv][d]);
    uos[wv][d] = uo;
    outp[OFF_UO + (size_t)b * 2 + d] = uo;
  }
  __syncthreads();

  if (l < 32) {
    int zh = zhs[wv];
    float t1 = uos[wv][0] + w_zd1[l * 10 + zh];
    float t2 = uos[wv][1] + w_zd2[l * 10 + zh];
    t1s[wv][l] = t1; t2s[wv][l] = t2;
    outp[OFF_T1 + (size_t)b * 32 + l] = t1;
    outp[OFF_T2 + (size_t)b * 32 + l] = t2;
  }
  __syncthreads();

  {
    float ax = 0.f, ay = 0.f, az = 0.f, aw = 0.f;
#pragma unroll 4
    for (int i = 0; i < 32; ++i) {
      float t1 = t1s[wv][i], t2 = t2s[wv][i];
      ushort4 wa = *(const ushort4*)(twL + i * 512 + l * 8);
      ushort4 wb = *(const ushort4*)(twL + i * 512 + l * 8 + 4);
      ushort4 tb = *(const ushort4*)(tbL + i * 256 + l * 4);
      float s;
      s = fmaf(t1, b2f(wa.x), fmaf(t2, b2f(wa.y), b2f(tb.x))); ax += fmaxf(s, 0.f);
      s = fmaf(t1, b2f(wa.z), fmaf(t2, b2f(wa.w), b2f(tb.y))); ay += fmaxf(s, 0.f);
      s = fmaf(t1, b2f(wb.x), fmaf(t2, b2f(wb.y), b2f(tb.z))); az += fmaxf(s, 0.f);
      s = fmaf(t1, b2f(wb.z), fmaf(t2, b2f(wb.w), b2f(tb.w))); aw += fmaxf(s, 0.f);
    }
    unsigned short pk[4] = {f2b(ax), f2b(ay), f2b(az), f2b(aw)};
    *(ushort4*)(xhb + (size_t)b * 256 + l * 4) = *(ushort4*)pk;
  }
}

// ---------------- dec3 MFMA ----------------
__global__ __launch_bounds__(256) void k_dec3m(const unsigned short* __restrict__ xhb,
    const unsigned short* __restrict__ w3t, const float* __restrict__ bias,
    unsigned short* __restrict__ d3t) {
  int t = threadIdx.x;
  int lane = t & 63, wv = t >> 6;
  int m0 = blockIdx.x * 64, n0 = blockIdx.y * 64;
  int l15 = lane & 15, g8 = (lane >> 4) * 8;
  const unsigned short* arow = xhb + (size_t)(m0 + wv * 16 + l15) * 256 + g8;
  const unsigned short* brow = w3t + (size_t)(n0 + l15) * 256 + g8;
  f32x4 acc[4] = {};
  for (int kb = 0; kb < 256; kb += 32) {
    bf16x8 af = *(const bf16x8*)(arow + kb);
#pragma unroll
    for (int ns = 0; ns < 4; ++ns) {
      bf16x8 bf = *(const bf16x8*)(brow + (size_t)ns * 4096 + kb);
      acc[ns] = __builtin_amdgcn_mfma_f32_16x16x32_bf16(af, bf, acc[ns], 0, 0, 0);
    }
  }
  int rbase = (lane >> 4) * 4;
#pragma unroll
  for (int ns = 0; ns < 4; ++ns) {
    int ncol = n0 + ns * 16 + l15;
    float bb = bias[ncol & 63];
#pragma unroll
    for (int r = 0; r < 4; ++r) {
      float v = fmaxf(acc[ns][r] + bb, 0.f);
      d3t[(size_t)(m0 + wv * 16 + rbase + r) * 1024 + ncol] = f2b(v);
    }
  }
}

// ---------------- dec2 MFMA + fused dec1 ----------------
__global__ __launch_bounds__(256) void k_dec2m(const unsigned short* __restrict__ d3t,
    const unsigned short* __restrict__ w2t, const float* __restrict__ b2,
    const float* __restrict__ w1, const float* __restrict__ b1,
    float* __restrict__ outp) {
  __shared__ unsigned short d2L[4][4096];
  __shared__ __align__(16) float w1s[256];
  __shared__ float b1s;
  int t = threadIdx.x;
  int lane = t & 63, wv = t >> 6;
  int m0 = blockIdx.x * 64;
  w1s[t] = w1[t];
  if (t == 0) b1s = b1[0];
  int l15 = lane & 15, g8 = (lane >> 4) * 8;
  const unsigned short* arow = d3t + (size_t)(m0 + wv * 16 + l15) * 64 + g8;
  bf16x8 af0 = *(const bf16x8*)(arow);
  bf16x8 af1 = *(const bf16x8*)(arow + 32);
  const unsigned short* brow = w2t + (size_t)l15 * 64 + g8;
  f32x4 acc[16] = {};
#pragma unroll
  for (int ns = 0; ns < 16; ++ns) {
    bf16x8 bf0 = *(const bf16x8*)(brow + (size_t)ns * 1024);
    bf16x8 bf1 = *(const bf16x8*)(brow + (size_t)ns * 1024 + 32);
    acc[ns] = __builtin_amdgcn_mfma_f32_16x16x32_bf16(af0, bf0, acc[ns], 0, 0, 0);
    acc[ns] = __builtin_amdgcn_mfma_f32_16x16x32_bf16(af1, bf1, acc[ns], 0, 0, 0);
  }
  int rbase = (lane >> 4) * 4;
  int pq_p = l15 >> 2, pq_q = l15 & 3;
#pragma unroll
  for (int ns = 0; ns < 16; ++ns) {
    float bb = b2[ns];
#pragma unroll
    for (int r = 0; r < 4; ++r) {
      int pos = rbase + r;
      float v = fmaxf(acc[ns][r] + bb, 0.f);
      d2L[wv][ns * 256 + ((pos >> 2) * 4 + pq_p) * 16 + (pos & 3) * 4 + pq_q] = f2b(v);
    }
  }
  __syncthreads();
  int bg0 = m0 >> 4;
  for (int c4 = 0; c4 < 16; ++c4) {
    int v = t + 256 * c4;
    int bp = v >> 10;
    int I = (v & 1023) >> 4;
    int jpix = v & 15;
    int ipix = I >> 2, pp = I & 3;
    const unsigned short* dl = &d2L[bp][ipix * 16 + jpix];
    float4 o = make_float4(b1s, b1s, b1s, b1s);
#pragma unroll
    for (int c = 0; c < 16; ++c) {
      float dv = b2f(dl[c * 256]);
      float4 wv4 = *(const float4*)(w1s + c * 16 + pp * 4);
      o.x = fmaf(dv, wv4.x, o.x);
      o.y = fmaf(dv, wv4.y, o.y);
      o.z = fmaf(dv, wv4.z, o.z);
      o.w = fmaf(dv, wv4.w, o.w);
    }
    *(float4*)(outp + (size_t)(bg0 + bp) * 4096 + I * 64 + jpix * 4) = o;
  }
}

extern "C" void kernel_launch(void* const* d_in, const int* in_sizes, int n_in,
                              void* d_out, int out_size, void* d_ws, size_t ws_size,
                              hipStream_t stream) {
  const float* x       = (const float*)d_in[0];
  const float* conv1_w = (const float*)d_in[3];
  const float* conv1_b = (const float*)d_in[4];
  const float* conv2_w = (const float*)d_in[5];
  const float* conv2_b = (const float*)d_in[6];
  const float* conv3_w = (const float*)d_in[7];
  const float* conv3_b = (const float*)d_in[8];
  const float* w_xz    = (const float*)d_in[9];
  const float* w_label = (const float*)d_in[10];
  const float* w_zd1   = (const float*)d_in[11];
  const float* w_zd2   = (const float*)d_in[12];
  const float* w_xu    = (const float*)d_in[13];
  const float* w_mu    = (const float*)d_in[14];
  const float* w_logvar= (const float*)d_in[15];
  const float* tc_w    = (const float*)d_in[16];
  const float* tc_b    = (const float*)d_in[17];
  const float* dec3_w  = (const float*)d_in[18];
  const float* dec3_b  = (const float*)d_in[19];
  const float* dec2_w  = (const float*)d_in[20];
  const float* dec2_b  = (const float*)d_in[21];
  const float* dec1_w  = (const float*)d_in[22];
  const float* dec1_b  = (const float*)d_in[23];

  float* out = (float*)d_out;
  float* ws  = (float*)d_ws;

  float* big = out + OFF_XL;                         // h1t -> conv3 partials -> final out
  float* h2  = ws;                                   // fp32 h2 [0 .. 4M)
  unsigned short* d3t = (unsigned short*)ws;         // bf16 d3t reuses [0 .. 2M floats)
  unsigned short* xhb = (unsigned short*)(ws + 5242880);
  unsigned short* w3t = (unsigned short*)(ws + 5767168);
  unsigned short* w2t = (unsigned short*)(ws + 5898240);
  float* xzxu = ws + 5906432;

  k_prep<<<136, 256, 0, stream>>>(dec3_w, dec2_w, w3t, w2t);
  k_conv1<<<B_TOT, 256, 0, stream>>>(x, conv1_w, conv1_b, big);
  k_conv2g<<<512, 256, 0, stream>>>(big, conv2_w, conv2_b, h2);
  k_conv3p<<<dim3(32, 4, 4), 256, 0, stream>>>(h2, conv3_w, big);
  k_headA<<<64, 256, 0, stream>>>(big, conv3_b, w_xz, w_xu, xzxu);
  k_headB<<<B_TOT / 4, 256, 0, stream>>>(xzxu, w_label, w_zd1, w_zd2, w_mu,
                                         w_logvar, tc_w, tc_b, out, xhb);
  k_dec3m<<<dim3(64, 16), 256, 0, stream>>>(xhb, w3t, dec3_b, d3t);
  k_dec2m<<<1024, 256, 0, stream>>>(d3t, w2t, dec2_b, dec1_w, dec1_b, big);
}